// Round 4
// baseline (446.801 us; speedup 1.0000x reference)
//
#include <hip/hip_runtime.h>

typedef unsigned short u16;
typedef unsigned int u32;
typedef __attribute__((ext_vector_type(8))) short short8;
typedef __attribute__((ext_vector_type(4))) float f32x4;
typedef __attribute__((ext_vector_type(8))) unsigned short ushort8_t;

#define SEQ 2048
#define DIM 1024
#define DINNER 2048
#define NPROJ 33
#define NPROJ_PAD 48
#define LC 64   // chunk length
#define NC 32   // SEQ / LC

__device__ __forceinline__ u16 f2bf(float f) {
  union { float f; u32 u; } v; v.f = f;
  u32 r = (v.u + 0x7fffu + ((v.u >> 16) & 1u)) >> 16;
  return (u16)r;
}
__device__ __forceinline__ float bf2f(u16 s) {
  union { u32 u; float f; } v; v.u = ((u32)s) << 16;
  return v.f;
}
__device__ __forceinline__ float fexp2(float x) {
#if __has_builtin(__builtin_amdgcn_exp2f)
  return __builtin_amdgcn_exp2f(x);
#else
  return __expf(x * 0.69314718f);
#endif
}
// softplus, numerically stable, fast-math units
__device__ __forceinline__ float softplus(float x) {
  return fmaxf(x, 0.f) + __logf(1.f + __expf(-fabsf(x)));
}
__device__ __forceinline__ void async16(const void* g, void* l) {
  __builtin_amdgcn_global_load_lds(
      (const __attribute__((address_space(1))) u32*)g,
      (__attribute__((address_space(3))) u32*)l, 16, 0, 0);
}

// ---------------- cast kernels (float4 -> ushort4) ----------------
__global__ void cast_f2b_kernel(const float* __restrict__ src, u16* __restrict__ dst, int n4) {
  int i = blockIdx.x * 256 + threadIdx.x;
  if (i < n4) {
    float4 v = ((const float4*)src)[i];
    ushort4 o;
    o.x = f2bf(v.x); o.y = f2bf(v.y); o.z = f2bf(v.z); o.w = f2bf(v.w);
    ((ushort4*)dst)[i] = o;
  }
}

// x_proj_w (33,2048) -> padded bf16 (48,2048), rows 33..47 = 0
__global__ void cast_w2pad_kernel(const float* __restrict__ src, u16* __restrict__ dst) {
  int i = blockIdx.x * 256 + threadIdx.x;  // 48*2048
  int j = i >> 11, k = i & 2047;
  dst[i] = (j < NPROJ) ? f2bf(src[j * 2048 + k]) : (u16)0;
}

// ---------------- layernorm (row=1024) -> bf16 ----------------
__global__ __launch_bounds__(256) void ln_kernel(const float* __restrict__ x,
                                                 const float* __restrict__ w,
                                                 const float* __restrict__ b,
                                                 u16* __restrict__ h) {
  const int row = blockIdx.x;
  const int tid = threadIdx.x;
  const int lane = tid & 63, wave = tid >> 6;
  const float4 v = ((const float4*)(x + (size_t)row * DIM))[tid];
  float s = v.x + v.y + v.z + v.w;
  float q = v.x * v.x + v.y * v.y + v.z * v.z + v.w * v.w;
  for (int off = 32; off; off >>= 1) {
    s += __shfl_down(s, off);
    q += __shfl_down(q, off);
  }
  __shared__ float sbuf[8];
  if (lane == 0) { sbuf[wave] = s; sbuf[4 + wave] = q; }
  __syncthreads();
  float tot = sbuf[0] + sbuf[1] + sbuf[2] + sbuf[3];
  float totq = sbuf[4] + sbuf[5] + sbuf[6] + sbuf[7];
  const float mean = tot * (1.0f / DIM);
  const float var = totq * (1.0f / DIM) - mean * mean;
  const float rs = rsqrtf(var + 1e-5f);
  const float4 wv = ((const float4*)w)[tid];
  const float4 bv = ((const float4*)b)[tid];
  ushort4 o;
  o.x = f2bf((v.x - mean) * rs * wv.x + bv.x);
  o.y = f2bf((v.y - mean) * rs * wv.y + bv.y);
  o.z = f2bf((v.z - mean) * rs * wv.z + bv.z);
  o.w = f2bf((v.w - mean) * rs * wv.w + bv.w);
  ((ushort4*)(h + (size_t)row * DIM))[tid] = o;
}

// ---------------- bf16 GEMM, B^T input, 128x128 tile, bf16 out ----------------
__global__ __launch_bounds__(256) void gemm_bf16_kernel(const u16* __restrict__ A,
                                                        const u16* __restrict__ Bt,
                                                        u16* __restrict__ C,
                                                        int K, int N) {
  __shared__ u16 As[128 * 32];
  __shared__ u16 Bs[128 * 32];
  const int tid = threadIdx.x;
  const int lane = tid & 63, wave = tid >> 6;
  const int wm = wave >> 1, wn = wave & 1;
  const int row16 = lane & 15, quad = lane >> 4;
  const int bn = blockIdx.x, bm = blockIdx.y;
  f32x4 acc[4][4] = {};
  const u16* Ablk = A + (size_t)bm * 128 * K;
  const u16* Bblk = Bt + (size_t)bn * 128 * K;
  for (int k0 = 0; k0 < K; k0 += 32) {
#pragma unroll
    for (int i = 0; i < 2; ++i) {
      int c = tid + i * 256;
      int r = c >> 2, cc = (c & 3) * 8;
      async16(Ablk + (size_t)r * K + k0 + cc, &As[c * 8]);
      async16(Bblk + (size_t)r * K + k0 + cc, &Bs[c * 8]);
    }
    __syncthreads();
    short8 af[4], bfr[4];
#pragma unroll
    for (int i = 0; i < 4; ++i) {
      af[i] = *(const short8*)&As[(wm * 64 + i * 16 + row16) * 32 + quad * 8];
      bfr[i] = *(const short8*)&Bs[(wn * 64 + i * 16 + row16) * 32 + quad * 8];
    }
#pragma unroll
    for (int i = 0; i < 4; ++i)
#pragma unroll
      for (int j = 0; j < 4; ++j)
        acc[i][j] = __builtin_amdgcn_mfma_f32_16x16x32_bf16(af[i], bfr[j], acc[i][j], 0, 0, 0);
    __syncthreads();
  }
#pragma unroll
  for (int i = 0; i < 4; ++i) {
    int m = bm * 128 + wm * 64 + i * 16 + quad * 4;
#pragma unroll
    for (int j = 0; j < 4; ++j) {
      int n = bn * 128 + wn * 64 + j * 16 + row16;
#pragma unroll
      for (int r = 0; r < 4; ++r)
        C[(size_t)(m + r) * N + n] = f2bf(acc[i][j][r]);
    }
  }
}

// ---------------- out GEMM: fp32 out + residual ----------------
__global__ __launch_bounds__(256) void gemm_out_kernel(const u16* __restrict__ A,
                                                       const u16* __restrict__ Bt,
                                                       const float* __restrict__ resid,
                                                       float* __restrict__ C,
                                                       int K, int N) {
  __shared__ u16 As[128 * 32];
  __shared__ u16 Bs[128 * 32];
  const int tid = threadIdx.x;
  const int lane = tid & 63, wave = tid >> 6;
  const int wm = wave >> 1, wn = wave & 1;
  const int row16 = lane & 15, quad = lane >> 4;
  const int bn = blockIdx.x, bm = blockIdx.y;
  f32x4 acc[4][4] = {};
  const u16* Ablk = A + (size_t)bm * 128 * K;
  const u16* Bblk = Bt + (size_t)bn * 128 * K;
  for (int k0 = 0; k0 < K; k0 += 32) {
#pragma unroll
    for (int i = 0; i < 2; ++i) {
      int c = tid + i * 256;
      int r = c >> 2, cc = (c & 3) * 8;
      async16(Ablk + (size_t)r * K + k0 + cc, &As[c * 8]);
      async16(Bblk + (size_t)r * K + k0 + cc, &Bs[c * 8]);
    }
    __syncthreads();
    short8 af[4], bfr[4];
#pragma unroll
    for (int i = 0; i < 4; ++i) {
      af[i] = *(const short8*)&As[(wm * 64 + i * 16 + row16) * 32 + quad * 8];
      bfr[i] = *(const short8*)&Bs[(wn * 64 + i * 16 + row16) * 32 + quad * 8];
    }
#pragma unroll
    for (int i = 0; i < 4; ++i)
#pragma unroll
      for (int j = 0; j < 4; ++j)
        acc[i][j] = __builtin_amdgcn_mfma_f32_16x16x32_bf16(af[i], bfr[j], acc[i][j], 0, 0, 0);
    __syncthreads();
  }
#pragma unroll
  for (int i = 0; i < 4; ++i) {
    int m = bm * 128 + wm * 64 + i * 16 + quad * 4;
#pragma unroll
    for (int j = 0; j < 4; ++j) {
      int n = bn * 128 + wn * 64 + j * 16 + row16;
#pragma unroll
      for (int r = 0; r < 4; ++r) {
        size_t idx = (size_t)(m + r) * N + n;
        C[idx] = acc[i][j][r] + resid[idx];
      }
    }
  }
}

// ---------------- causal depthwise conv (k=4) + SiLU, vectorized ----------------
__global__ __launch_bounds__(256) void conv_silu_kernel(const u16* __restrict__ c1,
                                                        const float* __restrict__ cw,
                                                        u16* __restrict__ cs) {
  const int tid = threadIdx.x;
  const int dg = tid * 8;
  const size_t m0 = (size_t)blockIdx.x * 8;
  const int l0 = (int)(m0 & (SEQ - 1));
  float w[4][8];
  {
    const float4* cw4 = (const float4*)(cw + (size_t)dg * 4);
#pragma unroll
    for (int c = 0; c < 8; ++c) {
      float4 v = cw4[c];
      w[0][c] = v.x; w[1][c] = v.y; w[2][c] = v.z; w[3][c] = v.w;
    }
  }
  const u16* base = c1 + m0 * DINNER + dg;
  ushort8_t win0, win1, win2, win3;
  const ushort8_t zero = (ushort8_t)0;
  if (l0 == 0) {
    win0 = zero; win1 = zero; win2 = zero;
  } else {
    win0 = *(const ushort8_t*)(base - 3 * DINNER);
    win1 = *(const ushort8_t*)(base - 2 * DINNER);
    win2 = *(const ushort8_t*)(base - 1 * DINNER);
  }
  win3 = *(const ushort8_t*)(base);
#pragma unroll
  for (int t = 0; t < 8; ++t) {
    ushort8_t nxt = win3;
    if (t < 7) nxt = *(const ushort8_t*)(base + (size_t)(t + 1) * DINNER);
    ushort8_t o;
#pragma unroll
    for (int c = 0; c < 8; ++c) {
      float acc = bf2f((u16)win0[c]) * w[0][c];
      acc = fmaf(bf2f((u16)win1[c]), w[1][c], acc);
      acc = fmaf(bf2f((u16)win2[c]), w[2][c], acc);
      acc = fmaf(bf2f((u16)win3[c]), w[3][c], acc);
      const float s = acc / (1.f + __expf(-acc));
      o[c] = (unsigned short)f2bf(s);
    }
    *(ushort8_t*)(cs + (m0 + t) * DINNER + dg) = o;
    win0 = win1; win1 = win2; win2 = win3; win3 = nxt;
  }
}

// ---------------- x_proj GEMM: M=8192, N=48(pad), K=2048 ----------------
__global__ __launch_bounds__(256) void gemm_w2_kernel(const u16* __restrict__ A,
                                                      const u16* __restrict__ Bt,
                                                      float* __restrict__ C) {
  __shared__ u16 As[128 * 32];
  __shared__ u16 Bs[48 * 32];
  const int tid = threadIdx.x;
  const int lane = tid & 63, wave = tid >> 6;
  const int row16 = lane & 15, quad = lane >> 4;
  const int bm = blockIdx.x;
  const int K = DINNER;
  f32x4 acc[2][3] = {};
  const u16* Ablk = A + (size_t)bm * 128 * K;
  for (int k0 = 0; k0 < K; k0 += 32) {
#pragma unroll
    for (int i = 0; i < 2; ++i) {
      int c = tid + i * 256;
      int r = c >> 2, cc = (c & 3) * 8;
      async16(Ablk + (size_t)r * K + k0 + cc, &As[c * 8]);
    }
    if (tid < 192) {
      int c = tid;
      int r = c >> 2, cc = (c & 3) * 8;
      async16(Bt + (size_t)r * K + k0 + cc, &Bs[c * 8]);
    }
    __syncthreads();
    short8 af[2], bfr[3];
#pragma unroll
    for (int i = 0; i < 2; ++i)
      af[i] = *(const short8*)&As[(wave * 32 + i * 16 + row16) * 32 + quad * 8];
#pragma unroll
    for (int j = 0; j < 3; ++j)
      bfr[j] = *(const short8*)&Bs[(j * 16 + row16) * 32 + quad * 8];
#pragma unroll
    for (int i = 0; i < 2; ++i)
#pragma unroll
      for (int j = 0; j < 3; ++j)
        acc[i][j] = __builtin_amdgcn_mfma_f32_16x16x32_bf16(af[i], bfr[j], acc[i][j], 0, 0, 0);
    __syncthreads();
  }
#pragma unroll
  for (int i = 0; i < 2; ++i) {
    int m = bm * 128 + wave * 32 + i * 16 + quad * 4;
#pragma unroll
    for (int j = 0; j < 3; ++j) {
      int n = j * 16 + row16;
#pragma unroll
      for (int r = 0; r < 4; ++r)
        C[(size_t)(m + r) * NPROJ_PAD + n] = acc[i][j][r];
    }
  }
}

// ======================= chunked selective scan =======================
// n-split layout: 1 thread = (channel d, half h) -> 8 states. 2 threads/channel.
// grid phase1/3: (DINNER/128, NC, B) = (16,32,4) = 2048 blocks, 8192 waves.

// ---- phase 1: local scan (init 0) -> S_loc, Tdt ----
__global__ __launch_bounds__(256) void scan_phase1(const float* __restrict__ proj,
                                                   const u16* __restrict__ xs,
                                                   const float* __restrict__ dtw_,
                                                   const float* __restrict__ dtb_,
                                                   const float* __restrict__ A_log,
                                                   float* __restrict__ S,
                                                   float* __restrict__ Tdt) {
  __shared__ float Bs[LC][16];
  __shared__ float DTin[LC];
  const int tid = threadIdx.x;
  const int half = tid & 1;
  const int d = blockIdx.x * 128 + (tid >> 1);
  const int c = blockIdx.y;
  const int b = blockIdx.z;
  const size_t mrow = (size_t)b * SEQ + c * LC;
  for (int i = tid; i < LC * 16; i += 256) {
    int t = i >> 4, n = i & 15;
    Bs[t][n] = proj[(mrow + t) * NPROJ_PAD + 1 + n];
  }
  if (tid < LC) DTin[tid] = proj[(mrow + tid) * NPROJ_PAD];
  __syncthreads();
  float An2[8];
#pragma unroll
  for (int n = 0; n < 8; ++n) An2[n] = -__expf(A_log[d * 16 + half * 8 + n]) * 1.44269504f;
  const float dtw = dtw_[d], dtb = dtb_[d];
  float s[8];
#pragma unroll
  for (int n = 0; n < 8; ++n) s[n] = 0.f;
  float Tsum = 0.f;
  const u16* xp = xs + mrow * DINNER + d;
  u16 xnext = *xp;
#pragma unroll 2
  for (int t = 0; t < LC; ++t) {
    const float xv = bf2f(xnext);
    if (t + 1 < LC) xnext = xp[(size_t)(t + 1) * DINNER];
    const float sp = softplus(fmaf(DTin[t], dtw, dtb));
    Tsum += sp;
    const float4 B0 = *(const float4*)&Bs[t][half * 8];
    const float4 B1 = *(const float4*)&Bs[t][half * 8 + 4];
    const float bb[8] = {B0.x, B0.y, B0.z, B0.w, B1.x, B1.y, B1.z, B1.w};
#pragma unroll
    for (int n = 0; n < 8; ++n)
      s[n] = fmaf(fexp2(An2[n] * sp), s[n], bb[n] * xv);
  }
  const size_t so = ((size_t)(b * NC + c) * DINNER + d) * 16 + half * 8;
  *(float4*)(S + so) = make_float4(s[0], s[1], s[2], s[3]);
  *(float4*)(S + so + 4) = make_float4(s[4], s[5], s[6], s[7]);
  if (half == 0) Tdt[(size_t)(b * NC + c) * DINNER + d] = Tsum;
}

// ---- phase 2: cross-chunk combine; S becomes per-chunk INIT state ----
__global__ __launch_bounds__(256) void scan_phase2(const float* __restrict__ A_log,
                                                   float* __restrict__ S,
                                                   const float* __restrict__ Tdt,
                                                   float* __restrict__ out_state) {
  const int idx = blockIdx.x * 256 + threadIdx.x;  // 8192 = B*DINNER
  const int b = idx >> 11, d = idx & (DINNER - 1);
  float An2[16];
#pragma unroll
  for (int n = 0; n < 16; ++n) An2[n] = -__expf(A_log[d * 16 + n]) * 1.44269504f;
  float prev[16];
#pragma unroll
  for (int n = 0; n < 16; ++n) prev[n] = 0.f;
  for (int c = 0; c < NC; ++c) {
    const size_t so = ((size_t)(b * NC + c) * DINNER + d) * 16;
    const float T = Tdt[(size_t)(b * NC + c) * DINNER + d];
    float loc[16];
#pragma unroll
    for (int n4 = 0; n4 < 4; ++n4) {
      float4 v = *(const float4*)(S + so + n4 * 4);
      loc[n4 * 4] = v.x; loc[n4 * 4 + 1] = v.y; loc[n4 * 4 + 2] = v.z; loc[n4 * 4 + 3] = v.w;
    }
#pragma unroll
    for (int n4 = 0; n4 < 4; ++n4)
      *(float4*)(S + so + n4 * 4) =
          make_float4(prev[n4 * 4], prev[n4 * 4 + 1], prev[n4 * 4 + 2], prev[n4 * 4 + 3]);
#pragma unroll
    for (int n = 0; n < 16; ++n)
      prev[n] = fmaf(fexp2(An2[n] * T), prev[n], loc[n]);
  }
  // final state, layout [b][d][n] fp32
#pragma unroll
  for (int n4 = 0; n4 < 4; ++n4)
    *(float4*)(out_state + ((size_t)b * DINNER + d) * 16 + n4 * 4) =
        make_float4(prev[n4 * 4], prev[n4 * 4 + 1], prev[n4 * 4 + 2], prev[n4 * 4 + 3]);
}

// ---- phase 3: re-scan chunk from init state, emit silu(y) ----
__global__ __launch_bounds__(256) void scan_phase3(const float* __restrict__ proj,
                                                   const u16* __restrict__ xs,
                                                   const float* __restrict__ dtw_,
                                                   const float* __restrict__ dtb_,
                                                   const float* __restrict__ A_log,
                                                   const float* __restrict__ Dp,
                                                   const float* __restrict__ S,
                                                   u16* __restrict__ ysil) {
  __shared__ float Bs[LC][16];
  __shared__ float Cs[LC][16];
  __shared__ float DTin[LC];
  const int tid = threadIdx.x;
  const int half = tid & 1;
  const int d = blockIdx.x * 128 + (tid >> 1);
  const int c = blockIdx.y;
  const int b = blockIdx.z;
  const size_t mrow = (size_t)b * SEQ + c * LC;
  for (int i = tid; i < LC * 16; i += 256) {
    int t = i >> 4, n = i & 15;
    Bs[t][n] = proj[(mrow + t) * NPROJ_PAD + 1 + n];
    Cs[t][n] = proj[(mrow + t) * NPROJ_PAD + 17 + n];
  }
  if (tid < LC) DTin[tid] = proj[(mrow + tid) * NPROJ_PAD];
  __syncthreads();
  float An2[8];
#pragma unroll
  for (int n = 0; n < 8; ++n) An2[n] = -__expf(A_log[d * 16 + half * 8 + n]) * 1.44269504f;
  const float dtw = dtw_[d], dtb = dtb_[d], Dd = Dp[d];
  float s[8];
  const size_t so = ((size_t)(b * NC + c) * DINNER + d) * 16 + half * 8;
  {
    float4 v0 = *(const float4*)(S + so);
    float4 v1 = *(const float4*)(S + so + 4);
    s[0] = v0.x; s[1] = v0.y; s[2] = v0.z; s[3] = v0.w;
    s[4] = v1.x; s[5] = v1.y; s[6] = v1.z; s[7] = v1.w;
  }
  const u16* xp = xs + mrow * DINNER + d;
  u16* yp = ysil + mrow * DINNER + d;
  u16 xnext = *xp;
#pragma unroll 2
  for (int t = 0; t < LC; ++t) {
    const float xv = bf2f(xnext);
    if (t + 1 < LC) xnext = xp[(size_t)(t + 1) * DINNER];
    const float sp = softplus(fmaf(DTin[t], dtw, dtb));
    const float4 B0 = *(const float4*)&Bs[t][half * 8];
    const float4 B1 = *(const float4*)&Bs[t][half * 8 + 4];
    const float bb[8] = {B0.x, B0.y, B0.z, B0.w, B1.x, B1.y, B1.z, B1.w};
#pragma unroll
    for (int n = 0; n < 8; ++n)
      s[n] = fmaf(fexp2(An2[n] * sp), s[n], bb[n] * xv);
    const float4 C0 = *(const float4*)&Cs[t][half * 8];
    const float4 C1 = *(const float4*)&Cs[t][half * 8 + 4];
    const float cc[8] = {C0.x, C0.y, C0.z, C0.w, C1.x, C1.y, C1.z, C1.w};
    float part = (half == 0) ? Dd * xv : 0.f;
#pragma unroll
    for (int n = 0; n < 8; ++n) part = fmaf(cc[n], s[n], part);
    const float y = part + __shfl_xor(part, 1);
    if (half == 0) {
      const float sy = y / (1.f + __expf(-y));
      yp[(size_t)t * DINNER] = f2bf(sy);
    }
  }
}

// ---------------- launch ----------------
extern "C" void kernel_launch(void* const* d_in, const int* in_sizes, int n_in,
                              void* d_out, int out_size, void* d_ws, size_t ws_size,
                              hipStream_t stream) {
  const float* x = (const float*)d_in[0];
  const float* in_proj_w = (const float*)d_in[1];
  const float* conv_w = (const float*)d_in[2];
  const float* x_proj_w = (const float*)d_in[3];
  const float* dt_proj_w = (const float*)d_in[4];
  const float* dt_proj_b = (const float*)d_in[5];
  const float* A_log = (const float*)d_in[6];
  const float* Dvec = (const float*)d_in[7];
  const float* out_proj_w = (const float*)d_in[8];
  const float* norm_w = (const float*)d_in[9];
  const float* norm_b = (const float*)d_in[10];

  char* ws = (char*)d_ws;
  u16* h = (u16*)(ws + 0);                    // 8192x1024 bf16 (16 MB)
  u16* w1b = (u16*)(ws + 16777216);           // 2048x1024 bf16 (4 MB)
  u16* w3b = (u16*)(ws + 20971520);           // 1024x2048 bf16 (4 MB)
  u16* w2b = (u16*)(ws + 25165824);           // 48x2048 bf16 (0.19 MB)
  u16* c1 = (u16*)(ws + 25362432);            // 8192x2048 bf16 (32 MB)
  u16* ysil = c1;                             // aliased: c1 dead after conv
  u16* cs = (u16*)(ws + 58916864);            // 8192x2048 bf16 (32 MB)
  float* proj = (float*)(ws + 92471296);      // 8192x48 fp32 (1.5 MB)
  float* Sbuf = (float*)(ws + 94044160);      // [b][c][d][n] fp32 (16 MB)
  float* Tdt = (float*)(ws + 110821376);      // [b][c][d] fp32 (1 MB)

  float* out = (float*)d_out;
  float* out_state = out + (size_t)4 * SEQ * DIM;

  cast_f2b_kernel<<<2048, 256, 0, stream>>>(in_proj_w, w1b, DINNER * DIM / 4);
  cast_f2b_kernel<<<2048, 256, 0, stream>>>(out_proj_w, w3b, DIM * DINNER / 4);
  cast_w2pad_kernel<<<384, 256, 0, stream>>>(x_proj_w, w2b);
  ln_kernel<<<8192, 256, 0, stream>>>(x, norm_w, norm_b, h);
  gemm_bf16_kernel<<<dim3(DINNER / 128, 64), 256, 0, stream>>>(h, w1b, c1, DIM, DINNER);
  conv_silu_kernel<<<1024, 256, 0, stream>>>(c1, conv_w, cs);
  gemm_w2_kernel<<<64, 256, 0, stream>>>(cs, w2b, proj);
  scan_phase1<<<dim3(DINNER / 128, NC, 4), 256, 0, stream>>>(proj, cs, dt_proj_w, dt_proj_b,
                                                             A_log, Sbuf, Tdt);
  scan_phase2<<<32, 256, 0, stream>>>(A_log, Sbuf, Tdt, out_state);
  scan_phase3<<<dim3(DINNER / 128, NC, 4), 256, 0, stream>>>(proj, cs, dt_proj_w, dt_proj_b,
                                                             A_log, Dvec, Sbuf, ysil);
  gemm_out_kernel<<<dim3(DIM / 128, 64), 256, 0, stream>>>(ysil, w3b, x, out, DINNER, DIM);
}

// Round 5
// 395.393 us; speedup vs baseline: 1.1300x; 1.1300x over previous
//
#include <hip/hip_runtime.h>

typedef unsigned short u16;
typedef unsigned int u32;
typedef __attribute__((ext_vector_type(8))) short short8;
typedef __attribute__((ext_vector_type(4))) float f32x4;
typedef __attribute__((ext_vector_type(8))) unsigned short ushort8_t;

#define SEQ 2048
#define DIM 1024
#define DINNER 2048
#define NPROJ 33
#define NPROJ_PAD 48
#define LC 32   // chunk length
#define NC 64   // SEQ / LC

__device__ __forceinline__ u16 f2bf(float f) {
  union { float f; u32 u; } v; v.f = f;
  u32 r = (v.u + 0x7fffu + ((v.u >> 16) & 1u)) >> 16;
  return (u16)r;
}
__device__ __forceinline__ float bf2f(u16 s) {
  union { u32 u; float f; } v; v.u = ((u32)s) << 16;
  return v.f;
}
__device__ __forceinline__ float fexp2(float x) {
#if __has_builtin(__builtin_amdgcn_exp2f)
  return __builtin_amdgcn_exp2f(x);
#else
  return __expf(x * 0.69314718f);
#endif
}
// softplus, numerically stable, fast-math units
__device__ __forceinline__ float softplus(float x) {
  return fmaxf(x, 0.f) + __logf(1.f + __expf(-fabsf(x)));
}
__device__ __forceinline__ void async16(const void* g, void* l) {
  __builtin_amdgcn_global_load_lds(
      (const __attribute__((address_space(1))) u32*)g,
      (__attribute__((address_space(3))) u32*)l, 16, 0, 0);
}

// ---------------- cast kernels ----------------
// both square weights (2048x1024 = 512K float4 items each) in one launch
__global__ void cast_w_kernel(const float* __restrict__ w1, const float* __restrict__ w3,
                              u16* __restrict__ o1, u16* __restrict__ o3) {
  int i = blockIdx.x * 256 + threadIdx.x;  // 524288
  float4 a = ((const float4*)w1)[i];
  float4 b = ((const float4*)w3)[i];
  ushort4 oa, ob;
  oa.x = f2bf(a.x); oa.y = f2bf(a.y); oa.z = f2bf(a.z); oa.w = f2bf(a.w);
  ob.x = f2bf(b.x); ob.y = f2bf(b.y); ob.z = f2bf(b.z); ob.w = f2bf(b.w);
  ((ushort4*)o1)[i] = oa;
  ((ushort4*)o3)[i] = ob;
}

// x_proj_w (33,2048) -> padded bf16 (48,2048), rows 33..47 = 0
__global__ void cast_w2pad_kernel(const float* __restrict__ src, u16* __restrict__ dst) {
  int i = blockIdx.x * 256 + threadIdx.x;  // 48*2048
  int j = i >> 11, k = i & 2047;
  dst[i] = (j < NPROJ) ? f2bf(src[j * 2048 + k]) : (u16)0;
}

// ---------------- layernorm (row=1024) -> bf16 ----------------
__global__ __launch_bounds__(256) void ln_kernel(const float* __restrict__ x,
                                                 const float* __restrict__ w,
                                                 const float* __restrict__ b,
                                                 u16* __restrict__ h) {
  const int row = blockIdx.x;
  const int tid = threadIdx.x;
  const int lane = tid & 63, wave = tid >> 6;
  const float4 v = ((const float4*)(x + (size_t)row * DIM))[tid];
  float s = v.x + v.y + v.z + v.w;
  float q = v.x * v.x + v.y * v.y + v.z * v.z + v.w * v.w;
  for (int off = 32; off; off >>= 1) {
    s += __shfl_down(s, off);
    q += __shfl_down(q, off);
  }
  __shared__ float sbuf[8];
  if (lane == 0) { sbuf[wave] = s; sbuf[4 + wave] = q; }
  __syncthreads();
  float tot = sbuf[0] + sbuf[1] + sbuf[2] + sbuf[3];
  float totq = sbuf[4] + sbuf[5] + sbuf[6] + sbuf[7];
  const float mean = tot * (1.0f / DIM);
  const float var = totq * (1.0f / DIM) - mean * mean;
  const float rs = rsqrtf(var + 1e-5f);
  const float4 wv = ((const float4*)w)[tid];
  const float4 bv = ((const float4*)b)[tid];
  ushort4 o;
  o.x = f2bf((v.x - mean) * rs * wv.x + bv.x);
  o.y = f2bf((v.y - mean) * rs * wv.y + bv.y);
  o.z = f2bf((v.z - mean) * rs * wv.z + bv.z);
  o.w = f2bf((v.w - mean) * rs * wv.w + bv.w);
  ((ushort4*)(h + (size_t)row * DIM))[tid] = o;
}

// ---------------- bf16 GEMM, B^T input, 128x128 tile, bf16 out ----------------
__global__ __launch_bounds__(256) void gemm_bf16_kernel(const u16* __restrict__ A,
                                                        const u16* __restrict__ Bt,
                                                        u16* __restrict__ C,
                                                        int K, int N) {
  __shared__ u16 As[128 * 32];
  __shared__ u16 Bs[128 * 32];
  const int tid = threadIdx.x;
  const int lane = tid & 63, wave = tid >> 6;
  const int wm = wave >> 1, wn = wave & 1;
  const int row16 = lane & 15, quad = lane >> 4;
  const int bn = blockIdx.x, bm = blockIdx.y;
  f32x4 acc[4][4] = {};
  const u16* Ablk = A + (size_t)bm * 128 * K;
  const u16* Bblk = Bt + (size_t)bn * 128 * K;
  for (int k0 = 0; k0 < K; k0 += 32) {
#pragma unroll
    for (int i = 0; i < 2; ++i) {
      int c = tid + i * 256;
      int r = c >> 2, cc = (c & 3) * 8;
      async16(Ablk + (size_t)r * K + k0 + cc, &As[c * 8]);
      async16(Bblk + (size_t)r * K + k0 + cc, &Bs[c * 8]);
    }
    __syncthreads();
    short8 af[4], bfr[4];
#pragma unroll
    for (int i = 0; i < 4; ++i) {
      af[i] = *(const short8*)&As[(wm * 64 + i * 16 + row16) * 32 + quad * 8];
      bfr[i] = *(const short8*)&Bs[(wn * 64 + i * 16 + row16) * 32 + quad * 8];
    }
#pragma unroll
    for (int i = 0; i < 4; ++i)
#pragma unroll
      for (int j = 0; j < 4; ++j)
        acc[i][j] = __builtin_amdgcn_mfma_f32_16x16x32_bf16(af[i], bfr[j], acc[i][j], 0, 0, 0);
    __syncthreads();
  }
#pragma unroll
  for (int i = 0; i < 4; ++i) {
    int m = bm * 128 + wm * 64 + i * 16 + quad * 4;
#pragma unroll
    for (int j = 0; j < 4; ++j) {
      int n = bn * 128 + wn * 64 + j * 16 + row16;
#pragma unroll
      for (int r = 0; r < 4; ++r)
        C[(size_t)(m + r) * N + n] = f2bf(acc[i][j][r]);
    }
  }
}

// ---------------- out GEMM: fp32 out + residual ----------------
__global__ __launch_bounds__(256) void gemm_out_kernel(const u16* __restrict__ A,
                                                       const u16* __restrict__ Bt,
                                                       const float* __restrict__ resid,
                                                       float* __restrict__ C,
                                                       int K, int N) {
  __shared__ u16 As[128 * 32];
  __shared__ u16 Bs[128 * 32];
  const int tid = threadIdx.x;
  const int lane = tid & 63, wave = tid >> 6;
  const int wm = wave >> 1, wn = wave & 1;
  const int row16 = lane & 15, quad = lane >> 4;
  const int bn = blockIdx.x, bm = blockIdx.y;
  f32x4 acc[4][4] = {};
  const u16* Ablk = A + (size_t)bm * 128 * K;
  const u16* Bblk = Bt + (size_t)bn * 128 * K;
  for (int k0 = 0; k0 < K; k0 += 32) {
#pragma unroll
    for (int i = 0; i < 2; ++i) {
      int c = tid + i * 256;
      int r = c >> 2, cc = (c & 3) * 8;
      async16(Ablk + (size_t)r * K + k0 + cc, &As[c * 8]);
      async16(Bblk + (size_t)r * K + k0 + cc, &Bs[c * 8]);
    }
    __syncthreads();
    short8 af[4], bfr[4];
#pragma unroll
    for (int i = 0; i < 4; ++i) {
      af[i] = *(const short8*)&As[(wm * 64 + i * 16 + row16) * 32 + quad * 8];
      bfr[i] = *(const short8*)&Bs[(wn * 64 + i * 16 + row16) * 32 + quad * 8];
    }
#pragma unroll
    for (int i = 0; i < 4; ++i)
#pragma unroll
      for (int j = 0; j < 4; ++j)
        acc[i][j] = __builtin_amdgcn_mfma_f32_16x16x32_bf16(af[i], bfr[j], acc[i][j], 0, 0, 0);
    __syncthreads();
  }
#pragma unroll
  for (int i = 0; i < 4; ++i) {
    int m = bm * 128 + wm * 64 + i * 16 + quad * 4;
#pragma unroll
    for (int j = 0; j < 4; ++j) {
      int n = bn * 128 + wn * 64 + j * 16 + row16;
#pragma unroll
      for (int r = 0; r < 4; ++r) {
        size_t idx = (size_t)(m + r) * N + n;
        C[idx] = acc[i][j][r] + resid[idx];
      }
    }
  }
}

// ---------------- causal depthwise conv (k=4) + SiLU, vectorized ----------------
__global__ __launch_bounds__(256) void conv_silu_kernel(const u16* __restrict__ c1,
                                                        const float* __restrict__ cw,
                                                        u16* __restrict__ cs) {
  const int tid = threadIdx.x;
  const int dg = tid * 8;
  const size_t m0 = (size_t)blockIdx.x * 8;
  const int l0 = (int)(m0 & (SEQ - 1));
  float w[4][8];
  {
    const float4* cw4 = (const float4*)(cw + (size_t)dg * 4);
#pragma unroll
    for (int c = 0; c < 8; ++c) {
      float4 v = cw4[c];
      w[0][c] = v.x; w[1][c] = v.y; w[2][c] = v.z; w[3][c] = v.w;
    }
  }
  const u16* base = c1 + m0 * DINNER + dg;
  ushort8_t win0, win1, win2, win3;
  const ushort8_t zero = (ushort8_t)0;
  if (l0 == 0) {
    win0 = zero; win1 = zero; win2 = zero;
  } else {
    win0 = *(const ushort8_t*)(base - 3 * DINNER);
    win1 = *(const ushort8_t*)(base - 2 * DINNER);
    win2 = *(const ushort8_t*)(base - 1 * DINNER);
  }
  win3 = *(const ushort8_t*)(base);
#pragma unroll
  for (int t = 0; t < 8; ++t) {
    ushort8_t nxt = win3;
    if (t < 7) nxt = *(const ushort8_t*)(base + (size_t)(t + 1) * DINNER);
    ushort8_t o;
#pragma unroll
    for (int c = 0; c < 8; ++c) {
      float acc = bf2f((u16)win0[c]) * w[0][c];
      acc = fmaf(bf2f((u16)win1[c]), w[1][c], acc);
      acc = fmaf(bf2f((u16)win2[c]), w[2][c], acc);
      acc = fmaf(bf2f((u16)win3[c]), w[3][c], acc);
      const float s = acc / (1.f + __expf(-acc));
      o[c] = (unsigned short)f2bf(s);
    }
    *(ushort8_t*)(cs + (m0 + t) * DINNER + dg) = o;
    win0 = win1; win1 = win2; win2 = win3; win3 = nxt;
  }
}

// ---------------- x_proj GEMM: M=8192, N=48(pad), K=2048 ----------------
__global__ __launch_bounds__(256) void gemm_w2_kernel(const u16* __restrict__ A,
                                                      const u16* __restrict__ Bt,
                                                      float* __restrict__ C) {
  __shared__ u16 As[128 * 32];
  __shared__ u16 Bs[48 * 32];
  const int tid = threadIdx.x;
  const int lane = tid & 63, wave = tid >> 6;
  const int row16 = lane & 15, quad = lane >> 4;
  const int bm = blockIdx.x;
  const int K = DINNER;
  f32x4 acc[2][3] = {};
  const u16* Ablk = A + (size_t)bm * 128 * K;
  for (int k0 = 0; k0 < K; k0 += 32) {
#pragma unroll
    for (int i = 0; i < 2; ++i) {
      int c = tid + i * 256;
      int r = c >> 2, cc = (c & 3) * 8;
      async16(Ablk + (size_t)r * K + k0 + cc, &As[c * 8]);
    }
    if (tid < 192) {
      int c = tid;
      int r = c >> 2, cc = (c & 3) * 8;
      async16(Bt + (size_t)r * K + k0 + cc, &Bs[c * 8]);
    }
    __syncthreads();
    short8 af[2], bfr[3];
#pragma unroll
    for (int i = 0; i < 2; ++i)
      af[i] = *(const short8*)&As[(wave * 32 + i * 16 + row16) * 32 + quad * 8];
#pragma unroll
    for (int j = 0; j < 3; ++j)
      bfr[j] = *(const short8*)&Bs[(j * 16 + row16) * 32 + quad * 8];
#pragma unroll
    for (int i = 0; i < 2; ++i)
#pragma unroll
      for (int j = 0; j < 3; ++j)
        acc[i][j] = __builtin_amdgcn_mfma_f32_16x16x32_bf16(af[i], bfr[j], acc[i][j], 0, 0, 0);
    __syncthreads();
  }
#pragma unroll
  for (int i = 0; i < 2; ++i) {
    int m = bm * 128 + wave * 32 + i * 16 + quad * 4;
#pragma unroll
    for (int j = 0; j < 3; ++j) {
      int n = j * 16 + row16;
#pragma unroll
      for (int r = 0; r < 4; ++r)
        C[(size_t)(m + r) * NPROJ_PAD + n] = acc[i][j][r];
    }
  }
}

// ======================= chunked selective scan =======================
// 1 thread = 1 channel (16 states in regs). LC=32, NC=64 -> 2048 blocks for
// phase1/3 (8 blocks/CU -> full wave-slot occupancy). S buffer is bf16.
// S layout: [b][c][d][16] u16; Tdt: [b][c][d] fp32.

// ---- phase 1: local scan (init 0) -> S_loc (bf16), Tdt ----
__global__ __launch_bounds__(256) void scan_phase1(const float* __restrict__ proj,
                                                   const u16* __restrict__ xs,
                                                   const float* __restrict__ dtw_,
                                                   const float* __restrict__ dtb_,
                                                   const float* __restrict__ A_log,
                                                   u16* __restrict__ S,
                                                   float* __restrict__ Tdt) {
  __shared__ float Bs[LC][16];
  __shared__ float DTin[LC];
  const int tid = threadIdx.x;
  const int d = blockIdx.x * 256 + tid;
  const int c = blockIdx.y;
  const int b = blockIdx.z;
  const size_t mrow = (size_t)b * SEQ + c * LC;
  for (int i = tid; i < LC * 16; i += 256) {
    int t = i >> 4, n = i & 15;
    Bs[t][n] = proj[(mrow + t) * NPROJ_PAD + 1 + n];
  }
  if (tid < LC) DTin[tid] = proj[(mrow + tid) * NPROJ_PAD];
  __syncthreads();
  float An2[16];
#pragma unroll
  for (int n = 0; n < 16; ++n) An2[n] = -__expf(A_log[d * 16 + n]) * 1.44269504f;
  const float dtw = dtw_[d], dtb = dtb_[d];
  float s[16];
#pragma unroll
  for (int n = 0; n < 16; ++n) s[n] = 0.f;
  float Tsum = 0.f;
  const u16* xp = xs + mrow * DINNER + d;
  u16 xnext = *xp;
#pragma unroll 2
  for (int t = 0; t < LC; ++t) {
    const float xv = bf2f(xnext);
    if (t + 1 < LC) xnext = xp[(size_t)(t + 1) * DINNER];
    const float sp = softplus(fmaf(DTin[t], dtw, dtb));
    Tsum += sp;
    const float4 B0 = *(const float4*)&Bs[t][0];
    const float4 B1 = *(const float4*)&Bs[t][4];
    const float4 B2 = *(const float4*)&Bs[t][8];
    const float4 B3 = *(const float4*)&Bs[t][12];
    const float bb[16] = {B0.x, B0.y, B0.z, B0.w, B1.x, B1.y, B1.z, B1.w,
                          B2.x, B2.y, B2.z, B2.w, B3.x, B3.y, B3.z, B3.w};
#pragma unroll
    for (int n = 0; n < 16; ++n)
      s[n] = fmaf(fexp2(An2[n] * sp), s[n], bb[n] * xv);
  }
  const size_t so = ((size_t)(b * NC + c) * DINNER + d) * 16;
  ushort8_t o0, o1;
#pragma unroll
  for (int j = 0; j < 8; ++j) {
    o0[j] = (unsigned short)f2bf(s[j]);
    o1[j] = (unsigned short)f2bf(s[8 + j]);
  }
  *(ushort8_t*)(S + so) = o0;
  *(ushort8_t*)(S + so + 8) = o1;
  Tdt[(size_t)(b * NC + c) * DINNER + d] = Tsum;
}

// ---- phase 2: cross-chunk combine; S becomes per-chunk INIT state ----
// 1 thread = (b, d, n-quad of 4 states); 32768 threads = 128 blocks.
__global__ __launch_bounds__(256) void scan_phase2(const float* __restrict__ A_log,
                                                   u16* __restrict__ S,
                                                   const float* __restrict__ Tdt,
                                                   float* __restrict__ out_state) {
  const int idx = blockIdx.x * 256 + threadIdx.x;  // B*DINNER*4
  const int nq = idx & 3;
  const int d = (idx >> 2) & (DINNER - 1);
  const int b = idx >> 13;
  float An2[4];
#pragma unroll
  for (int n = 0; n < 4; ++n) An2[n] = -__expf(A_log[d * 16 + nq * 4 + n]) * 1.44269504f;
  float prev[4] = {0.f, 0.f, 0.f, 0.f};
  for (int c = 0; c < NC; ++c) {
    const size_t base = (size_t)(b * NC + c) * DINNER + d;
    const float T = Tdt[base];
    const size_t so = base * 16 + nq * 4;
    ushort4 lv = *(const ushort4*)(S + so);
    const float loc[4] = {bf2f(lv.x), bf2f(lv.y), bf2f(lv.z), bf2f(lv.w)};
    ushort4 pv;
    pv.x = f2bf(prev[0]); pv.y = f2bf(prev[1]); pv.z = f2bf(prev[2]); pv.w = f2bf(prev[3]);
    *(ushort4*)(S + so) = pv;
    const float dk = fexp2(An2[0] * T), dk1 = fexp2(An2[1] * T);
    const float dk2 = fexp2(An2[2] * T), dk3 = fexp2(An2[3] * T);
    prev[0] = fmaf(dk, prev[0], loc[0]);
    prev[1] = fmaf(dk1, prev[1], loc[1]);
    prev[2] = fmaf(dk2, prev[2], loc[2]);
    prev[3] = fmaf(dk3, prev[3], loc[3]);
  }
  // final state, layout [b][d][n] fp32
  *(float4*)(out_state + ((size_t)b * DINNER + d) * 16 + nq * 4) =
      make_float4(prev[0], prev[1], prev[2], prev[3]);
}

// ---- phase 3: re-scan chunk from init state, emit silu(y) ----
__global__ __launch_bounds__(256) void scan_phase3(const float* __restrict__ proj,
                                                   const u16* __restrict__ xs,
                                                   const float* __restrict__ dtw_,
                                                   const float* __restrict__ dtb_,
                                                   const float* __restrict__ A_log,
                                                   const float* __restrict__ Dp,
                                                   const u16* __restrict__ S,
                                                   u16* __restrict__ ysil) {
  __shared__ float Bs[LC][16];
  __shared__ float Cs[LC][16];
  __shared__ float DTin[LC];
  const int tid = threadIdx.x;
  const int d = blockIdx.x * 256 + tid;
  const int c = blockIdx.y;
  const int b = blockIdx.z;
  const size_t mrow = (size_t)b * SEQ + c * LC;
  for (int i = tid; i < LC * 16; i += 256) {
    int t = i >> 4, n = i & 15;
    Bs[t][n] = proj[(mrow + t) * NPROJ_PAD + 1 + n];
    Cs[t][n] = proj[(mrow + t) * NPROJ_PAD + 17 + n];
  }
  if (tid < LC) DTin[tid] = proj[(mrow + tid) * NPROJ_PAD];
  __syncthreads();
  float An2[16];
#pragma unroll
  for (int n = 0; n < 16; ++n) An2[n] = -__expf(A_log[d * 16 + n]) * 1.44269504f;
  const float dtw = dtw_[d], dtb = dtb_[d], Dd = Dp[d];
  float s[16];
  const size_t so = ((size_t)(b * NC + c) * DINNER + d) * 16;
  {
    ushort8_t v0 = *(const ushort8_t*)(S + so);
    ushort8_t v1 = *(const ushort8_t*)(S + so + 8);
#pragma unroll
    for (int j = 0; j < 8; ++j) {
      s[j] = bf2f((u16)v0[j]);
      s[8 + j] = bf2f((u16)v1[j]);
    }
  }
  const u16* xp = xs + mrow * DINNER + d;
  u16* yp = ysil + mrow * DINNER + d;
  u16 xnext = *xp;
#pragma unroll 2
  for (int t = 0; t < LC; ++t) {
    const float xv = bf2f(xnext);
    if (t + 1 < LC) xnext = xp[(size_t)(t + 1) * DINNER];
    const float sp = softplus(fmaf(DTin[t], dtw, dtb));
    const float4 B0 = *(const float4*)&Bs[t][0];
    const float4 B1 = *(const float4*)&Bs[t][4];
    const float4 B2 = *(const float4*)&Bs[t][8];
    const float4 B3 = *(const float4*)&Bs[t][12];
    const float bb[16] = {B0.x, B0.y, B0.z, B0.w, B1.x, B1.y, B1.z, B1.w,
                          B2.x, B2.y, B2.z, B2.w, B3.x, B3.y, B3.z, B3.w};
#pragma unroll
    for (int n = 0; n < 16; ++n)
      s[n] = fmaf(fexp2(An2[n] * sp), s[n], bb[n] * xv);
    const float4 C0 = *(const float4*)&Cs[t][0];
    const float4 C1 = *(const float4*)&Cs[t][4];
    const float4 C2 = *(const float4*)&Cs[t][8];
    const float4 C3 = *(const float4*)&Cs[t][12];
    const float cc[16] = {C0.x, C0.y, C0.z, C0.w, C1.x, C1.y, C1.z, C1.w,
                          C2.x, C2.y, C2.z, C2.w, C3.x, C3.y, C3.z, C3.w};
    float y = Dd * xv;
#pragma unroll
    for (int n = 0; n < 16; ++n) y = fmaf(cc[n], s[n], y);
    const float sy = y / (1.f + __expf(-y));
    yp[(size_t)t * DINNER] = f2bf(sy);
  }
}

// ---------------- launch ----------------
extern "C" void kernel_launch(void* const* d_in, const int* in_sizes, int n_in,
                              void* d_out, int out_size, void* d_ws, size_t ws_size,
                              hipStream_t stream) {
  const float* x = (const float*)d_in[0];
  const float* in_proj_w = (const float*)d_in[1];
  const float* conv_w = (const float*)d_in[2];
  const float* x_proj_w = (const float*)d_in[3];
  const float* dt_proj_w = (const float*)d_in[4];
  const float* dt_proj_b = (const float*)d_in[5];
  const float* A_log = (const float*)d_in[6];
  const float* Dvec = (const float*)d_in[7];
  const float* out_proj_w = (const float*)d_in[8];
  const float* norm_w = (const float*)d_in[9];
  const float* norm_b = (const float*)d_in[10];

  char* ws = (char*)d_ws;
  u16* h = (u16*)(ws + 0);                    // 8192x1024 bf16 (16 MB)
  u16* w1b = (u16*)(ws + 16777216);           // 2048x1024 bf16 (4 MB)
  u16* w3b = (u16*)(ws + 20971520);           // 1024x2048 bf16 (4 MB)
  u16* w2b = (u16*)(ws + 25165824);           // 48x2048 bf16 (0.19 MB)
  u16* c1 = (u16*)(ws + 25362432);            // 8192x2048 bf16 (32 MB)
  u16* ysil = c1;                             // aliased: c1 dead after conv
  u16* cs = (u16*)(ws + 58916864);            // 8192x2048 bf16 (32 MB)
  float* proj = (float*)(ws + 92471296);      // 8192x48 fp32 (1.5 MB)
  u16* Sbuf = (u16*)(ws + 94044160);          // [b][c][d][16] bf16 (16 MB)
  float* Tdt = (float*)(ws + 110821376);      // [b][c][d] fp32 (2 MB)

  float* out = (float*)d_out;
  float* out_state = out + (size_t)4 * SEQ * DIM;

  cast_w_kernel<<<2048, 256, 0, stream>>>(in_proj_w, out_proj_w, w1b, w3b);
  cast_w2pad_kernel<<<384, 256, 0, stream>>>(x_proj_w, w2b);
  ln_kernel<<<8192, 256, 0, stream>>>(x, norm_w, norm_b, h);
  gemm_bf16_kernel<<<dim3(DINNER / 128, 64), 256, 0, stream>>>(h, w1b, c1, DIM, DINNER);
  conv_silu_kernel<<<1024, 256, 0, stream>>>(c1, conv_w, cs);
  gemm_w2_kernel<<<64, 256, 0, stream>>>(cs, w2b, proj);
  scan_phase1<<<dim3(DINNER / 256, NC, 4), 256, 0, stream>>>(proj, cs, dt_proj_w, dt_proj_b,
                                                             A_log, Sbuf, Tdt);
  scan_phase2<<<128, 256, 0, stream>>>(A_log, Sbuf, Tdt, out_state);
  scan_phase3<<<dim3(DINNER / 256, NC, 4), 256, 0, stream>>>(proj, cs, dt_proj_w, dt_proj_b,
                                                             A_log, Dvec, Sbuf, ysil);
  gemm_out_kernel<<<dim3(DIM / 128, 64), 256, 0, stream>>>(ysil, w3b, x, out, DINNER, DIM);
}

// Round 6
// 385.182 us; speedup vs baseline: 1.1600x; 1.0265x over previous
//
#include <hip/hip_runtime.h>

typedef unsigned short u16;
typedef unsigned int u32;
typedef __attribute__((ext_vector_type(8))) short short8;
typedef __attribute__((ext_vector_type(4))) float f32x4;
typedef __attribute__((ext_vector_type(2))) float f32x2;
typedef __attribute__((ext_vector_type(8))) unsigned short ushort8_t;

#define SEQ 2048
#define DIM 1024
#define DINNER 2048
#define NPROJ 33
#define NPROJ_PAD 48
#define LC 32   // chunk length
#define NC 64   // SEQ / LC

__device__ __forceinline__ u16 f2bf(float f) {
  union { float f; u32 u; } v; v.f = f;
  u32 r = (v.u + 0x7fffu + ((v.u >> 16) & 1u)) >> 16;
  return (u16)r;
}
__device__ __forceinline__ float bf2f(u16 s) {
  union { u32 u; float f; } v; v.u = ((u32)s) << 16;
  return v.f;
}
__device__ __forceinline__ float lo_bf(u32 w) {
  union { u32 u; float f; } v; v.u = w << 16; return v.f;
}
__device__ __forceinline__ float hi_bf(u32 w) {
  union { u32 u; float f; } v; v.u = w & 0xffff0000u; return v.f;
}
__device__ __forceinline__ float fexp2(float x) {
#if __has_builtin(__builtin_amdgcn_exp2f)
  return __builtin_amdgcn_exp2f(x);
#else
  return __expf(x * 0.69314718f);
#endif
}
__device__ __forceinline__ float softplus(float x) {
  return fmaxf(x, 0.f) + __logf(1.f + __expf(-fabsf(x)));
}
__device__ __forceinline__ f32x2 sp2(float v) { f32x2 r; r.x = v; r.y = v; return r; }
__device__ __forceinline__ f32x2 pkfma(f32x2 a, f32x2 b, f32x2 c) {
  return __builtin_elementwise_fma(a, b, c);
}
__device__ __forceinline__ void async16(const void* g, void* l) {
  __builtin_amdgcn_global_load_lds(
      (const __attribute__((address_space(1))) u32*)g,
      (__attribute__((address_space(3))) u32*)l, 16, 0, 0);
}

// ---------------- cast kernels ----------------
__global__ void cast_w_kernel(const float* __restrict__ w1, const float* __restrict__ w3,
                              u16* __restrict__ o1, u16* __restrict__ o3) {
  int i = blockIdx.x * 256 + threadIdx.x;  // 524288
  float4 a = ((const float4*)w1)[i];
  float4 b = ((const float4*)w3)[i];
  ushort4 oa, ob;
  oa.x = f2bf(a.x); oa.y = f2bf(a.y); oa.z = f2bf(a.z); oa.w = f2bf(a.w);
  ob.x = f2bf(b.x); ob.y = f2bf(b.y); ob.z = f2bf(b.z); ob.w = f2bf(b.w);
  ((ushort4*)o1)[i] = oa;
  ((ushort4*)o3)[i] = ob;
}

__global__ void cast_w2pad_kernel(const float* __restrict__ src, u16* __restrict__ dst) {
  int i = blockIdx.x * 256 + threadIdx.x;  // 48*2048
  int j = i >> 11, k = i & 2047;
  dst[i] = (j < NPROJ) ? f2bf(src[j * 2048 + k]) : (u16)0;
}

// ---------------- layernorm (row=1024) -> bf16 ----------------
__global__ __launch_bounds__(256) void ln_kernel(const float* __restrict__ x,
                                                 const float* __restrict__ w,
                                                 const float* __restrict__ b,
                                                 u16* __restrict__ h) {
  const int row = blockIdx.x;
  const int tid = threadIdx.x;
  const int lane = tid & 63, wave = tid >> 6;
  const float4 v = ((const float4*)(x + (size_t)row * DIM))[tid];
  float s = v.x + v.y + v.z + v.w;
  float q = v.x * v.x + v.y * v.y + v.z * v.z + v.w * v.w;
  for (int off = 32; off; off >>= 1) {
    s += __shfl_down(s, off);
    q += __shfl_down(q, off);
  }
  __shared__ float sbuf[8];
  if (lane == 0) { sbuf[wave] = s; sbuf[4 + wave] = q; }
  __syncthreads();
  float tot = sbuf[0] + sbuf[1] + sbuf[2] + sbuf[3];
  float totq = sbuf[4] + sbuf[5] + sbuf[6] + sbuf[7];
  const float mean = tot * (1.0f / DIM);
  const float var = totq * (1.0f / DIM) - mean * mean;
  const float rs = rsqrtf(var + 1e-5f);
  const float4 wv = ((const float4*)w)[tid];
  const float4 bv = ((const float4*)b)[tid];
  ushort4 o;
  o.x = f2bf((v.x - mean) * rs * wv.x + bv.x);
  o.y = f2bf((v.y - mean) * rs * wv.y + bv.y);
  o.z = f2bf((v.z - mean) * rs * wv.z + bv.z);
  o.w = f2bf((v.w - mean) * rs * wv.w + bv.w);
  ((ushort4*)(h + (size_t)row * DIM))[tid] = o;
}

// ---------------- bf16 GEMM, B^T input, 128x128 tile, 512 thr (8 waves) ----------------
// wave tile 64(M)x32(N): af[4], bfr[2], acc[4][2]. grid = (N/128, M/128).
__global__ __launch_bounds__(512) void gemm_bf16_kernel(const u16* __restrict__ A,
                                                        const u16* __restrict__ Bt,
                                                        u16* __restrict__ C,
                                                        int K, int N) {
  __shared__ u16 As[128 * 32];
  __shared__ u16 Bs[128 * 32];
  const int tid = threadIdx.x;
  const int lane = tid & 63, wave = tid >> 6;
  const int wm = wave >> 2, wn = wave & 3;
  const int row16 = lane & 15, quad = lane >> 4;
  const int bn = blockIdx.x, bm = blockIdx.y;
  f32x4 acc[4][2] = {};
  const u16* Ablk = A + (size_t)bm * 128 * K;
  const u16* Bblk = Bt + (size_t)bn * 128 * K;
  const int r = tid >> 2, cc = (tid & 3) * 8;
  for (int k0 = 0; k0 < K; k0 += 32) {
    async16(Ablk + (size_t)r * K + k0 + cc, &As[tid * 8]);
    async16(Bblk + (size_t)r * K + k0 + cc, &Bs[tid * 8]);
    __syncthreads();
    short8 af[4], bfr[2];
#pragma unroll
    for (int i = 0; i < 4; ++i)
      af[i] = *(const short8*)&As[(wm * 64 + i * 16 + row16) * 32 + quad * 8];
#pragma unroll
    for (int j = 0; j < 2; ++j)
      bfr[j] = *(const short8*)&Bs[(wn * 32 + j * 16 + row16) * 32 + quad * 8];
#pragma unroll
    for (int i = 0; i < 4; ++i)
#pragma unroll
      for (int j = 0; j < 2; ++j)
        acc[i][j] = __builtin_amdgcn_mfma_f32_16x16x32_bf16(af[i], bfr[j], acc[i][j], 0, 0, 0);
    __syncthreads();
  }
#pragma unroll
  for (int i = 0; i < 4; ++i) {
    int m = bm * 128 + wm * 64 + i * 16 + quad * 4;
#pragma unroll
    for (int j = 0; j < 2; ++j) {
      int n = bn * 128 + wn * 32 + j * 16 + row16;
#pragma unroll
      for (int rr = 0; rr < 4; ++rr)
        C[(size_t)(m + rr) * N + n] = f2bf(acc[i][j][rr]);
    }
  }
}

// ---------------- out GEMM: fp32 out + residual, 512 thr ----------------
__global__ __launch_bounds__(512) void gemm_out_kernel(const u16* __restrict__ A,
                                                       const u16* __restrict__ Bt,
                                                       const float* __restrict__ resid,
                                                       float* __restrict__ C,
                                                       int K, int N) {
  __shared__ u16 As[128 * 32];
  __shared__ u16 Bs[128 * 32];
  const int tid = threadIdx.x;
  const int lane = tid & 63, wave = tid >> 6;
  const int wm = wave >> 2, wn = wave & 3;
  const int row16 = lane & 15, quad = lane >> 4;
  const int bn = blockIdx.x, bm = blockIdx.y;
  f32x4 acc[4][2] = {};
  const u16* Ablk = A + (size_t)bm * 128 * K;
  const u16* Bblk = Bt + (size_t)bn * 128 * K;
  const int r = tid >> 2, cc = (tid & 3) * 8;
  for (int k0 = 0; k0 < K; k0 += 32) {
    async16(Ablk + (size_t)r * K + k0 + cc, &As[tid * 8]);
    async16(Bblk + (size_t)r * K + k0 + cc, &Bs[tid * 8]);
    __syncthreads();
    short8 af[4], bfr[2];
#pragma unroll
    for (int i = 0; i < 4; ++i)
      af[i] = *(const short8*)&As[(wm * 64 + i * 16 + row16) * 32 + quad * 8];
#pragma unroll
    for (int j = 0; j < 2; ++j)
      bfr[j] = *(const short8*)&Bs[(wn * 32 + j * 16 + row16) * 32 + quad * 8];
#pragma unroll
    for (int i = 0; i < 4; ++i)
#pragma unroll
      for (int j = 0; j < 2; ++j)
        acc[i][j] = __builtin_amdgcn_mfma_f32_16x16x32_bf16(af[i], bfr[j], acc[i][j], 0, 0, 0);
    __syncthreads();
  }
#pragma unroll
  for (int i = 0; i < 4; ++i) {
    int m = bm * 128 + wm * 64 + i * 16 + quad * 4;
#pragma unroll
    for (int j = 0; j < 2; ++j) {
      int n = bn * 128 + wn * 32 + j * 16 + row16;
#pragma unroll
      for (int rr = 0; rr < 4; ++rr) {
        size_t idx = (size_t)(m + rr) * N + n;
        C[idx] = acc[i][j][rr] + resid[idx];
      }
    }
  }
}

// ---------------- causal depthwise conv (k=4) + SiLU, vectorized ----------------
__global__ __launch_bounds__(256) void conv_silu_kernel(const u16* __restrict__ c1,
                                                        const float* __restrict__ cw,
                                                        u16* __restrict__ cs) {
  const int tid = threadIdx.x;
  const int dg = tid * 8;
  const size_t m0 = (size_t)blockIdx.x * 8;
  const int l0 = (int)(m0 & (SEQ - 1));
  float w[4][8];
  {
    const float4* cw4 = (const float4*)(cw + (size_t)dg * 4);
#pragma unroll
    for (int c = 0; c < 8; ++c) {
      float4 v = cw4[c];
      w[0][c] = v.x; w[1][c] = v.y; w[2][c] = v.z; w[3][c] = v.w;
    }
  }
  const u16* base = c1 + m0 * DINNER + dg;
  ushort8_t win0, win1, win2, win3;
  const ushort8_t zero = (ushort8_t)0;
  if (l0 == 0) {
    win0 = zero; win1 = zero; win2 = zero;
  } else {
    win0 = *(const ushort8_t*)(base - 3 * DINNER);
    win1 = *(const ushort8_t*)(base - 2 * DINNER);
    win2 = *(const ushort8_t*)(base - 1 * DINNER);
  }
  win3 = *(const ushort8_t*)(base);
#pragma unroll
  for (int t = 0; t < 8; ++t) {
    ushort8_t nxt = win3;
    if (t < 7) nxt = *(const ushort8_t*)(base + (size_t)(t + 1) * DINNER);
    ushort8_t o;
#pragma unroll
    for (int c = 0; c < 8; ++c) {
      float acc = bf2f((u16)win0[c]) * w[0][c];
      acc = fmaf(bf2f((u16)win1[c]), w[1][c], acc);
      acc = fmaf(bf2f((u16)win2[c]), w[2][c], acc);
      acc = fmaf(bf2f((u16)win3[c]), w[3][c], acc);
      const float s = acc / (1.f + __expf(-acc));
      o[c] = (unsigned short)f2bf(s);
    }
    *(ushort8_t*)(cs + (m0 + t) * DINNER + dg) = o;
    win0 = win1; win1 = win2; win2 = win3; win3 = nxt;
  }
}

// ---------------- x_proj GEMM: M-tile 64, N=48(pad), K=2048; grid 128 ----------------
__global__ __launch_bounds__(256) void gemm_w2_kernel(const u16* __restrict__ A,
                                                      const u16* __restrict__ Bt,
                                                      float* __restrict__ C) {
  __shared__ u16 As[64 * 32];
  __shared__ u16 Bs[48 * 32];
  const int tid = threadIdx.x;
  const int lane = tid & 63, wave = tid >> 6;
  const int row16 = lane & 15, quad = lane >> 4;
  const int bm = blockIdx.x;
  const int K = DINNER;
  f32x4 acc[3] = {};
  const u16* Ablk = A + (size_t)bm * 64 * K;
  const int r = tid >> 2, cc = (tid & 3) * 8;
  for (int k0 = 0; k0 < K; k0 += 32) {
    async16(Ablk + (size_t)r * K + k0 + cc, &As[tid * 8]);
    if (tid < 192) async16(Bt + (size_t)r * K + k0 + cc, &Bs[tid * 8]);
    __syncthreads();
    short8 af = *(const short8*)&As[(wave * 16 + row16) * 32 + quad * 8];
    short8 bfr[3];
#pragma unroll
    for (int j = 0; j < 3; ++j)
      bfr[j] = *(const short8*)&Bs[(j * 16 + row16) * 32 + quad * 8];
#pragma unroll
    for (int j = 0; j < 3; ++j)
      acc[j] = __builtin_amdgcn_mfma_f32_16x16x32_bf16(af, bfr[j], acc[j], 0, 0, 0);
    __syncthreads();
  }
  const int m = bm * 64 + wave * 16 + quad * 4;
#pragma unroll
  for (int j = 0; j < 3; ++j) {
    const int n = j * 16 + row16;
#pragma unroll
    for (int rr = 0; rr < 4; ++rr)
      C[(size_t)(m + rr) * NPROJ_PAD + n] = acc[j][rr];
  }
}

// ======================= chunked selective scan =======================
// 1 thread = 2 adjacent channels, 16 states each, packed f32x2 math.
// grid phase1/3: (DINNER/512, NC, B) = (4,64,4) = 1024 blocks.
// S layout: [b][c][d][16] bf16; Tdt: [b][c][d] fp32.

// ---- phase 1: local scan (init 0) -> S_loc (bf16), Tdt ----
__global__ __launch_bounds__(256) void scan_phase1(const float* __restrict__ proj,
                                                   const u16* __restrict__ xs,
                                                   const float* __restrict__ dtw_,
                                                   const float* __restrict__ dtb_,
                                                   const float* __restrict__ A_log,
                                                   u16* __restrict__ S,
                                                   float* __restrict__ Tdt) {
  __shared__ float Bsh[LC][16];
  __shared__ float DTin[LC];
  const int tid = threadIdx.x;
  const int d0 = blockIdx.x * 512 + tid * 2;
  const int c = blockIdx.y;
  const int b = blockIdx.z;
  const size_t mrow = (size_t)b * SEQ + c * LC;
  for (int i = tid; i < LC * 16; i += 256) {
    int t = i >> 4, n = i & 15;
    Bsh[t][n] = proj[(mrow + t) * NPROJ_PAD + 1 + n];
  }
  if (tid < LC) DTin[tid] = proj[(mrow + tid) * NPROJ_PAD];
  __syncthreads();
  f32x2 An2[16];
#pragma unroll
  for (int n = 0; n < 16; ++n) {
    An2[n].x = -__expf(A_log[(size_t)d0 * 16 + n]) * 1.44269504f;
    An2[n].y = -__expf(A_log[(size_t)(d0 + 1) * 16 + n]) * 1.44269504f;
  }
  const float2 dtwv = *(const float2*)(dtw_ + d0);
  const float2 dtbv = *(const float2*)(dtb_ + d0);
  f32x2 dtw2; dtw2.x = dtwv.x; dtw2.y = dtwv.y;
  f32x2 dtb2; dtb2.x = dtbv.x; dtb2.y = dtbv.y;
  f32x2 s[16];
#pragma unroll
  for (int n = 0; n < 16; ++n) s[n] = sp2(0.f);
  f32x2 Tsum = sp2(0.f);
  const u16* xp = xs + mrow * DINNER + d0;
  u32 xw = *(const u32*)xp;
#pragma unroll 2
  for (int t = 0; t < LC; ++t) {
    f32x2 xv; xv.x = lo_bf(xw); xv.y = hi_bf(xw);
    if (t + 1 < LC) xw = *(const u32*)(xp + (size_t)(t + 1) * DINNER);
    f32x2 dtv = pkfma(sp2(DTin[t]), dtw2, dtb2);
    f32x2 sp; sp.x = softplus(dtv.x); sp.y = softplus(dtv.y);
    Tsum += sp;
    const float4* Br = (const float4*)&Bsh[t][0];
#pragma unroll
    for (int q = 0; q < 4; ++q) {
      const float4 Bq = Br[q];
      const float bqa[4] = {Bq.x, Bq.y, Bq.z, Bq.w};
#pragma unroll
      for (int j = 0; j < 4; ++j) {
        const int n = q * 4 + j;
        f32x2 e = An2[n] * sp;
        f32x2 dk; dk.x = fexp2(e.x); dk.y = fexp2(e.y);
        s[n] = pkfma(dk, s[n], sp2(bqa[j]) * xv);
      }
    }
  }
  const size_t so = ((size_t)(b * NC + c) * DINNER + d0) * 16;
  ushort8_t o0, o1, o2, o3;
#pragma unroll
  for (int j = 0; j < 8; ++j) {
    o0[j] = f2bf(s[j].x);     o1[j] = f2bf(s[8 + j].x);
    o2[j] = f2bf(s[j].y);     o3[j] = f2bf(s[8 + j].y);
  }
  *(ushort8_t*)(S + so) = o0;       *(ushort8_t*)(S + so + 8) = o1;
  *(ushort8_t*)(S + so + 16) = o2;  *(ushort8_t*)(S + so + 24) = o3;
  *(float2*)(Tdt + (size_t)(b * NC + c) * DINNER + d0) = make_float2(Tsum.x, Tsum.y);
}

// ---- phase 2: cross-chunk combine; S becomes per-chunk INIT state ----
__global__ __launch_bounds__(256) void scan_phase2(const float* __restrict__ A_log,
                                                   u16* __restrict__ S,
                                                   const float* __restrict__ Tdt,
                                                   float* __restrict__ out_state) {
  const int idx = blockIdx.x * 256 + threadIdx.x;  // B*DINNER*4
  const int nq = idx & 3;
  const int d = (idx >> 2) & (DINNER - 1);
  const int b = idx >> 13;
  float An2[4];
#pragma unroll
  for (int n = 0; n < 4; ++n) An2[n] = -__expf(A_log[d * 16 + nq * 4 + n]) * 1.44269504f;
  float prev[4] = {0.f, 0.f, 0.f, 0.f};
  for (int c = 0; c < NC; ++c) {
    const size_t base = (size_t)(b * NC + c) * DINNER + d;
    const float T = Tdt[base];
    const size_t so = base * 16 + nq * 4;
    ushort4 lv = *(const ushort4*)(S + so);
    const float loc[4] = {bf2f(lv.x), bf2f(lv.y), bf2f(lv.z), bf2f(lv.w)};
    ushort4 pv;
    pv.x = f2bf(prev[0]); pv.y = f2bf(prev[1]); pv.z = f2bf(prev[2]); pv.w = f2bf(prev[3]);
    *(ushort4*)(S + so) = pv;
    const float dk0 = fexp2(An2[0] * T), dk1 = fexp2(An2[1] * T);
    const float dk2 = fexp2(An2[2] * T), dk3 = fexp2(An2[3] * T);
    prev[0] = fmaf(dk0, prev[0], loc[0]);
    prev[1] = fmaf(dk1, prev[1], loc[1]);
    prev[2] = fmaf(dk2, prev[2], loc[2]);
    prev[3] = fmaf(dk3, prev[3], loc[3]);
  }
  *(float4*)(out_state + ((size_t)b * DINNER + d) * 16 + nq * 4) =
      make_float4(prev[0], prev[1], prev[2], prev[3]);
}

// ---- phase 3: re-scan chunk from init state, emit silu(y) ----
__global__ __launch_bounds__(256) void scan_phase3(const float* __restrict__ proj,
                                                   const u16* __restrict__ xs,
                                                   const float* __restrict__ dtw_,
                                                   const float* __restrict__ dtb_,
                                                   const float* __restrict__ A_log,
                                                   const float* __restrict__ Dp,
                                                   const u16* __restrict__ S,
                                                   u16* __restrict__ ysil) {
  __shared__ float Bsh[LC][16];
  __shared__ float Csh[LC][16];
  __shared__ float DTin[LC];
  const int tid = threadIdx.x;
  const int d0 = blockIdx.x * 512 + tid * 2;
  const int c = blockIdx.y;
  const int b = blockIdx.z;
  const size_t mrow = (size_t)b * SEQ + c * LC;
  for (int i = tid; i < LC * 16; i += 256) {
    int t = i >> 4, n = i & 15;
    Bsh[t][n] = proj[(mrow + t) * NPROJ_PAD + 1 + n];
    Csh[t][n] = proj[(mrow + t) * NPROJ_PAD + 17 + n];
  }
  if (tid < LC) DTin[tid] = proj[(mrow + tid) * NPROJ_PAD];
  __syncthreads();
  f32x2 An2[16];
#pragma unroll
  for (int n = 0; n < 16; ++n) {
    An2[n].x = -__expf(A_log[(size_t)d0 * 16 + n]) * 1.44269504f;
    An2[n].y = -__expf(A_log[(size_t)(d0 + 1) * 16 + n]) * 1.44269504f;
  }
  const float2 dtwv = *(const float2*)(dtw_ + d0);
  const float2 dtbv = *(const float2*)(dtb_ + d0);
  const float2 Ddv = *(const float2*)(Dp + d0);
  f32x2 dtw2; dtw2.x = dtwv.x; dtw2.y = dtwv.y;
  f32x2 dtb2; dtb2.x = dtbv.x; dtb2.y = dtbv.y;
  f32x2 Dd2; Dd2.x = Ddv.x; Dd2.y = Ddv.y;
  f32x2 s[16];
  const size_t so = ((size_t)(b * NC + c) * DINNER + d0) * 16;
  {
    ushort8_t v0 = *(const ushort8_t*)(S + so);
    ushort8_t v1 = *(const ushort8_t*)(S + so + 8);
    ushort8_t v2 = *(const ushort8_t*)(S + so + 16);
    ushort8_t v3 = *(const ushort8_t*)(S + so + 24);
#pragma unroll
    for (int j = 0; j < 8; ++j) {
      s[j].x = bf2f((u16)v0[j]);     s[8 + j].x = bf2f((u16)v1[j]);
      s[j].y = bf2f((u16)v2[j]);     s[8 + j].y = bf2f((u16)v3[j]);
    }
  }
  const u16* xp = xs + mrow * DINNER + d0;
  u16* yp = ysil + mrow * DINNER + d0;
  u32 xw = *(const u32*)xp;
#pragma unroll 2
  for (int t = 0; t < LC; ++t) {
    f32x2 xv; xv.x = lo_bf(xw); xv.y = hi_bf(xw);
    if (t + 1 < LC) xw = *(const u32*)(xp + (size_t)(t + 1) * DINNER);
    f32x2 dtv = pkfma(sp2(DTin[t]), dtw2, dtb2);
    f32x2 sp; sp.x = softplus(dtv.x); sp.y = softplus(dtv.y);
    f32x2 y = Dd2 * xv;
    const float4* Br = (const float4*)&Bsh[t][0];
    const float4* Cr = (const float4*)&Csh[t][0];
#pragma unroll
    for (int q = 0; q < 4; ++q) {
      const float4 Bq = Br[q];
      const float4 Cq = Cr[q];
      const float bqa[4] = {Bq.x, Bq.y, Bq.z, Bq.w};
      const float cqa[4] = {Cq.x, Cq.y, Cq.z, Cq.w};
#pragma unroll
      for (int j = 0; j < 4; ++j) {
        const int n = q * 4 + j;
        f32x2 e = An2[n] * sp;
        f32x2 dk; dk.x = fexp2(e.x); dk.y = fexp2(e.y);
        s[n] = pkfma(dk, s[n], sp2(bqa[j]) * xv);
        y = pkfma(sp2(cqa[j]), s[n], y);
      }
    }
    const float sy0 = y.x / (1.f + __expf(-y.x));
    const float sy1 = y.y / (1.f + __expf(-y.y));
    const u32 ow = (u32)f2bf(sy0) | ((u32)f2bf(sy1) << 16);
    *(u32*)(yp + (size_t)t * DINNER) = ow;
  }
}

// ---------------- launch ----------------
extern "C" void kernel_launch(void* const* d_in, const int* in_sizes, int n_in,
                              void* d_out, int out_size, void* d_ws, size_t ws_size,
                              hipStream_t stream) {
  const float* x = (const float*)d_in[0];
  const float* in_proj_w = (const float*)d_in[1];
  const float* conv_w = (const float*)d_in[2];
  const float* x_proj_w = (const float*)d_in[3];
  const float* dt_proj_w = (const float*)d_in[4];
  const float* dt_proj_b = (const float*)d_in[5];
  const float* A_log = (const float*)d_in[6];
  const float* Dvec = (const float*)d_in[7];
  const float* out_proj_w = (const float*)d_in[8];
  const float* norm_w = (const float*)d_in[9];
  const float* norm_b = (const float*)d_in[10];

  char* ws = (char*)d_ws;
  u16* h = (u16*)(ws + 0);                    // 8192x1024 bf16 (16 MB)
  u16* w1b = (u16*)(ws + 16777216);           // 2048x1024 bf16 (4 MB)
  u16* w3b = (u16*)(ws + 20971520);           // 1024x2048 bf16 (4 MB)
  u16* w2b = (u16*)(ws + 25165824);           // 48x2048 bf16 (0.19 MB)
  u16* c1 = (u16*)(ws + 25362432);            // 8192x2048 bf16 (32 MB)
  u16* ysil = c1;                             // aliased: c1 dead after conv
  u16* cs = (u16*)(ws + 58916864);            // 8192x2048 bf16 (32 MB)
  float* proj = (float*)(ws + 92471296);      // 8192x48 fp32 (1.5 MB)
  u16* Sbuf = (u16*)(ws + 94044160);          // [b][c][d][16] bf16 (16 MB)
  float* Tdt = (float*)(ws + 110821376);      // [b][c][d] fp32 (2 MB)

  float* out = (float*)d_out;
  float* out_state = out + (size_t)4 * SEQ * DIM;

  cast_w_kernel<<<2048, 256, 0, stream>>>(in_proj_w, out_proj_w, w1b, w3b);
  cast_w2pad_kernel<<<384, 256, 0, stream>>>(x_proj_w, w2b);
  ln_kernel<<<8192, 256, 0, stream>>>(x, norm_w, norm_b, h);
  gemm_bf16_kernel<<<dim3(DINNER / 128, 64), 512, 0, stream>>>(h, w1b, c1, DIM, DINNER);
  conv_silu_kernel<<<1024, 256, 0, stream>>>(c1, conv_w, cs);
  gemm_w2_kernel<<<128, 256, 0, stream>>>(cs, w2b, proj);
  scan_phase1<<<dim3(DINNER / 512, NC, 4), 256, 0, stream>>>(proj, cs, dt_proj_w, dt_proj_b,
                                                             A_log, Sbuf, Tdt);
  scan_phase2<<<128, 256, 0, stream>>>(A_log, Sbuf, Tdt, out_state);
  scan_phase3<<<dim3(DINNER / 512, NC, 4), 256, 0, stream>>>(proj, cs, dt_proj_w, dt_proj_b,
                                                             A_log, Dvec, Sbuf, ysil);
  gemm_out_kernel<<<dim3(DIM / 128, 64), 512, 0, stream>>>(ysil, w3b, x, out, DINNER, DIM);
}

// Round 7
// 374.236 us; speedup vs baseline: 1.1939x; 1.0292x over previous
//
#include <hip/hip_runtime.h>

typedef unsigned short u16;
typedef unsigned int u32;
typedef __attribute__((ext_vector_type(8))) short short8;
typedef __attribute__((ext_vector_type(4))) float f32x4;
typedef __attribute__((ext_vector_type(2))) float f32x2;
typedef __attribute__((ext_vector_type(8))) unsigned short ushort8_t;

#define SEQ 2048
#define DIM 1024
#define DINNER 2048
#define NPROJ 33
#define NPROJ_PAD 48
#define LC 32   // chunk length
#define NC 64   // SEQ / LC

__device__ __forceinline__ u16 f2bf(float f) {
  union { float f; u32 u; } v; v.f = f;
  u32 r = (v.u + 0x7fffu + ((v.u >> 16) & 1u)) >> 16;
  return (u16)r;
}
__device__ __forceinline__ float bf2f(u16 s) {
  union { u32 u; float f; } v; v.u = ((u32)s) << 16;
  return v.f;
}
__device__ __forceinline__ float lo_bf(u32 w) {
  union { u32 u; float f; } v; v.u = w << 16; return v.f;
}
__device__ __forceinline__ float hi_bf(u32 w) {
  union { u32 u; float f; } v; v.u = w & 0xffff0000u; return v.f;
}
__device__ __forceinline__ float fexp2(float x) {
#if __has_builtin(__builtin_amdgcn_exp2f)
  return __builtin_amdgcn_exp2f(x);
#else
  return __expf(x * 0.69314718f);
#endif
}
__device__ __forceinline__ float softplus(float x) {
  return fmaxf(x, 0.f) + __logf(1.f + __expf(-fabsf(x)));
}
__device__ __forceinline__ f32x2 sp2(float v) { f32x2 r; r.x = v; r.y = v; return r; }
__device__ __forceinline__ f32x2 pkfma(f32x2 a, f32x2 b, f32x2 c) {
  return __builtin_elementwise_fma(a, b, c);
}
__device__ __forceinline__ void async16(const void* g, void* l) {
  __builtin_amdgcn_global_load_lds(
      (const __attribute__((address_space(1))) u32*)g,
      (__attribute__((address_space(3))) u32*)l, 16, 0, 0);
}

// ---------------- cast kernels ----------------
__global__ void cast_w_kernel(const float* __restrict__ w1, const float* __restrict__ w3,
                              u16* __restrict__ o1, u16* __restrict__ o3) {
  int i = blockIdx.x * 256 + threadIdx.x;  // 524288
  float4 a = ((const float4*)w1)[i];
  float4 b = ((const float4*)w3)[i];
  ushort4 oa, ob;
  oa.x = f2bf(a.x); oa.y = f2bf(a.y); oa.z = f2bf(a.z); oa.w = f2bf(a.w);
  ob.x = f2bf(b.x); ob.y = f2bf(b.y); ob.z = f2bf(b.z); ob.w = f2bf(b.w);
  ((ushort4*)o1)[i] = oa;
  ((ushort4*)o3)[i] = ob;
}

__global__ void cast_w2pad_kernel(const float* __restrict__ src, u16* __restrict__ dst) {
  int i = blockIdx.x * 256 + threadIdx.x;  // 48*2048
  int j = i >> 11, k = i & 2047;
  dst[i] = (j < NPROJ) ? f2bf(src[j * 2048 + k]) : (u16)0;
}

// ---------------- layernorm (row=1024) -> bf16 ----------------
__global__ __launch_bounds__(256) void ln_kernel(const float* __restrict__ x,
                                                 const float* __restrict__ w,
                                                 const float* __restrict__ b,
                                                 u16* __restrict__ h) {
  const int row = blockIdx.x;
  const int tid = threadIdx.x;
  const int lane = tid & 63, wave = tid >> 6;
  const float4 v = ((const float4*)(x + (size_t)row * DIM))[tid];
  float s = v.x + v.y + v.z + v.w;
  float q = v.x * v.x + v.y * v.y + v.z * v.z + v.w * v.w;
  for (int off = 32; off; off >>= 1) {
    s += __shfl_down(s, off);
    q += __shfl_down(q, off);
  }
  __shared__ float sbuf[8];
  if (lane == 0) { sbuf[wave] = s; sbuf[4 + wave] = q; }
  __syncthreads();
  float tot = sbuf[0] + sbuf[1] + sbuf[2] + sbuf[3];
  float totq = sbuf[4] + sbuf[5] + sbuf[6] + sbuf[7];
  const float mean = tot * (1.0f / DIM);
  const float var = totq * (1.0f / DIM) - mean * mean;
  const float rs = rsqrtf(var + 1e-5f);
  const float4 wv = ((const float4*)w)[tid];
  const float4 bv = ((const float4*)b)[tid];
  ushort4 o;
  o.x = f2bf((v.x - mean) * rs * wv.x + bv.x);
  o.y = f2bf((v.y - mean) * rs * wv.y + bv.y);
  o.z = f2bf((v.z - mean) * rs * wv.z + bv.z);
  o.w = f2bf((v.w - mean) * rs * wv.w + bv.w);
  ((ushort4*)(h + (size_t)row * DIM))[tid] = o;
}

// ---------------- bf16 GEMM, B^T input, 128x128 tile, 512 thr (8 waves) ----------------
// XCD swizzle: each XCD owns an 8-panel A slice (L2-resident), streams B panels.
__global__ __launch_bounds__(512) void gemm_bf16_kernel(const u16* __restrict__ A,
                                                        const u16* __restrict__ Bt,
                                                        u16* __restrict__ C,
                                                        int K, int N) {
  __shared__ u16 As[128 * 32];
  __shared__ u16 Bs[128 * 32];
  const int tid = threadIdx.x;
  const int lane = tid & 63, wave = tid >> 6;
  const int wm = wave >> 2, wn = wave & 3;
  const int row16 = lane & 15, quad = lane >> 4;
  const int flat = blockIdx.x + gridDim.x * blockIdx.y;
  const int xcd = flat & 7;
  const int sidx = flat >> 3;
  const int bm = xcd * 8 + (sidx & 7);   // 64 bm panels, 8 per XCD
  const int bn = sidx >> 3;
  f32x4 acc[4][2] = {};
  const u16* Ablk = A + (size_t)bm * 128 * K;
  const u16* Bblk = Bt + (size_t)bn * 128 * K;
  const int r = tid >> 2, cc = (tid & 3) * 8;
  for (int k0 = 0; k0 < K; k0 += 32) {
    async16(Ablk + (size_t)r * K + k0 + cc, &As[tid * 8]);
    async16(Bblk + (size_t)r * K + k0 + cc, &Bs[tid * 8]);
    __syncthreads();
    short8 af[4], bfr[2];
#pragma unroll
    for (int i = 0; i < 4; ++i)
      af[i] = *(const short8*)&As[(wm * 64 + i * 16 + row16) * 32 + quad * 8];
#pragma unroll
    for (int j = 0; j < 2; ++j)
      bfr[j] = *(const short8*)&Bs[(wn * 32 + j * 16 + row16) * 32 + quad * 8];
#pragma unroll
    for (int i = 0; i < 4; ++i)
#pragma unroll
      for (int j = 0; j < 2; ++j)
        acc[i][j] = __builtin_amdgcn_mfma_f32_16x16x32_bf16(af[i], bfr[j], acc[i][j], 0, 0, 0);
    __syncthreads();
  }
#pragma unroll
  for (int i = 0; i < 4; ++i) {
    int m = bm * 128 + wm * 64 + i * 16 + quad * 4;
#pragma unroll
    for (int j = 0; j < 2; ++j) {
      int n = bn * 128 + wn * 32 + j * 16 + row16;
#pragma unroll
      for (int rr = 0; rr < 4; ++rr)
        C[(size_t)(m + rr) * N + n] = f2bf(acc[i][j][rr]);
    }
  }
}

// ---------------- out GEMM: fp32 out + residual, 512 thr, XCD swizzle ----------------
__global__ __launch_bounds__(512) void gemm_out_kernel(const u16* __restrict__ A,
                                                       const u16* __restrict__ Bt,
                                                       const float* __restrict__ resid,
                                                       float* __restrict__ C,
                                                       int K, int N) {
  __shared__ u16 As[128 * 32];
  __shared__ u16 Bs[128 * 32];
  const int tid = threadIdx.x;
  const int lane = tid & 63, wave = tid >> 6;
  const int wm = wave >> 2, wn = wave & 3;
  const int row16 = lane & 15, quad = lane >> 4;
  const int flat = blockIdx.x + gridDim.x * blockIdx.y;
  const int xcd = flat & 7;
  const int sidx = flat >> 3;
  const int bm = xcd * 8 + (sidx & 7);
  const int bn = sidx >> 3;
  f32x4 acc[4][2] = {};
  const u16* Ablk = A + (size_t)bm * 128 * K;
  const u16* Bblk = Bt + (size_t)bn * 128 * K;
  const int r = tid >> 2, cc = (tid & 3) * 8;
  for (int k0 = 0; k0 < K; k0 += 32) {
    async16(Ablk + (size_t)r * K + k0 + cc, &As[tid * 8]);
    async16(Bblk + (size_t)r * K + k0 + cc, &Bs[tid * 8]);
    __syncthreads();
    short8 af[4], bfr[2];
#pragma unroll
    for (int i = 0; i < 4; ++i)
      af[i] = *(const short8*)&As[(wm * 64 + i * 16 + row16) * 32 + quad * 8];
#pragma unroll
    for (int j = 0; j < 2; ++j)
      bfr[j] = *(const short8*)&Bs[(wn * 32 + j * 16 + row16) * 32 + quad * 8];
#pragma unroll
    for (int i = 0; i < 4; ++i)
#pragma unroll
      for (int j = 0; j < 2; ++j)
        acc[i][j] = __builtin_amdgcn_mfma_f32_16x16x32_bf16(af[i], bfr[j], acc[i][j], 0, 0, 0);
    __syncthreads();
  }
#pragma unroll
  for (int i = 0; i < 4; ++i) {
    int m = bm * 128 + wm * 64 + i * 16 + quad * 4;
#pragma unroll
    for (int j = 0; j < 2; ++j) {
      int n = bn * 128 + wn * 32 + j * 16 + row16;
#pragma unroll
      for (int rr = 0; rr < 4; ++rr) {
        size_t idx = (size_t)(m + rr) * N + n;
        C[idx] = acc[i][j][rr] + resid[idx];
      }
    }
  }
}

// ---------------- causal depthwise conv (k=4) + SiLU, vectorized ----------------
__global__ __launch_bounds__(256) void conv_silu_kernel(const u16* __restrict__ c1,
                                                        const float* __restrict__ cw,
                                                        u16* __restrict__ cs) {
  const int tid = threadIdx.x;
  const int dg = tid * 8;
  const size_t m0 = (size_t)blockIdx.x * 8;
  const int l0 = (int)(m0 & (SEQ - 1));
  float w[4][8];
  {
    const float4* cw4 = (const float4*)(cw + (size_t)dg * 4);
#pragma unroll
    for (int c = 0; c < 8; ++c) {
      float4 v = cw4[c];
      w[0][c] = v.x; w[1][c] = v.y; w[2][c] = v.z; w[3][c] = v.w;
    }
  }
  const u16* base = c1 + m0 * DINNER + dg;
  ushort8_t win0, win1, win2, win3;
  const ushort8_t zero = (ushort8_t)0;
  if (l0 == 0) {
    win0 = zero; win1 = zero; win2 = zero;
  } else {
    win0 = *(const ushort8_t*)(base - 3 * DINNER);
    win1 = *(const ushort8_t*)(base - 2 * DINNER);
    win2 = *(const ushort8_t*)(base - 1 * DINNER);
  }
  win3 = *(const ushort8_t*)(base);
#pragma unroll
  for (int t = 0; t < 8; ++t) {
    ushort8_t nxt = win3;
    if (t < 7) nxt = *(const ushort8_t*)(base + (size_t)(t + 1) * DINNER);
    ushort8_t o;
#pragma unroll
    for (int c = 0; c < 8; ++c) {
      float acc = bf2f((u16)win0[c]) * w[0][c];
      acc = fmaf(bf2f((u16)win1[c]), w[1][c], acc);
      acc = fmaf(bf2f((u16)win2[c]), w[2][c], acc);
      acc = fmaf(bf2f((u16)win3[c]), w[3][c], acc);
      const float s = acc / (1.f + __expf(-acc));
      o[c] = (unsigned short)f2bf(s);
    }
    *(ushort8_t*)(cs + (m0 + t) * DINNER + dg) = o;
    win0 = win1; win1 = win2; win2 = win3; win3 = nxt;
  }
}

// ---------------- x_proj GEMM: M-tile 64, N=48(pad), K=2048; grid 128 ----------------
__global__ __launch_bounds__(256) void gemm_w2_kernel(const u16* __restrict__ A,
                                                      const u16* __restrict__ Bt,
                                                      float* __restrict__ C) {
  __shared__ u16 As[64 * 32];
  __shared__ u16 Bs[48 * 32];
  const int tid = threadIdx.x;
  const int lane = tid & 63, wave = tid >> 6;
  const int row16 = lane & 15, quad = lane >> 4;
  const int bm = blockIdx.x;
  const int K = DINNER;
  f32x4 acc[3] = {};
  const u16* Ablk = A + (size_t)bm * 64 * K;
  const int r = tid >> 2, cc = (tid & 3) * 8;
  for (int k0 = 0; k0 < K; k0 += 32) {
    async16(Ablk + (size_t)r * K + k0 + cc, &As[tid * 8]);
    if (tid < 192) async16(Bt + (size_t)r * K + k0 + cc, &Bs[tid * 8]);
    __syncthreads();
    short8 af = *(const short8*)&As[(wave * 16 + row16) * 32 + quad * 8];
    short8 bfr[3];
#pragma unroll
    for (int j = 0; j < 3; ++j)
      bfr[j] = *(const short8*)&Bs[(j * 16 + row16) * 32 + quad * 8];
#pragma unroll
    for (int j = 0; j < 3; ++j)
      acc[j] = __builtin_amdgcn_mfma_f32_16x16x32_bf16(af, bfr[j], acc[j], 0, 0, 0);
    __syncthreads();
  }
  const int m = bm * 64 + wave * 16 + quad * 4;
#pragma unroll
  for (int j = 0; j < 3; ++j) {
    const int n = j * 16 + row16;
#pragma unroll
    for (int rr = 0; rr < 4; ++rr)
      C[(size_t)(m + rr) * NPROJ_PAD + n] = acc[j][rr];
  }
}

// ======================= chunked selective scan =======================
// 1 thread = 2 adjacent channels (packed f32x2), 128-thread blocks.
// grid phase1/3: (DINNER/256, NC, B) = (8,64,4) = 2048 blocks x 2 waves
// = 8192 waves (full 32-wave/CU cap) with packed issue volume.
// S layout: [b][c][d][16] bf16; Tdt: [b][c][d] fp32.

// ---- phase 1: local scan (init 0) -> S_loc (bf16), Tdt ----
__global__ __launch_bounds__(128) void scan_phase1(const float* __restrict__ proj,
                                                   const u16* __restrict__ xs,
                                                   const float* __restrict__ dtw_,
                                                   const float* __restrict__ dtb_,
                                                   const float* __restrict__ A_log,
                                                   u16* __restrict__ S,
                                                   float* __restrict__ Tdt) {
  __shared__ float Bsh[LC][16];
  __shared__ float DTin[LC];
  const int tid = threadIdx.x;
  const int d0 = blockIdx.x * 256 + tid * 2;
  const int c = blockIdx.y;
  const int b = blockIdx.z;
  const size_t mrow = (size_t)b * SEQ + c * LC;
  for (int i = tid; i < LC * 16; i += 128) {
    int t = i >> 4, n = i & 15;
    Bsh[t][n] = proj[(mrow + t) * NPROJ_PAD + 1 + n];
  }
  if (tid < LC) DTin[tid] = proj[(mrow + tid) * NPROJ_PAD];
  __syncthreads();
  f32x2 An2[16];
#pragma unroll
  for (int n = 0; n < 16; ++n) {
    An2[n].x = -__expf(A_log[(size_t)d0 * 16 + n]) * 1.44269504f;
    An2[n].y = -__expf(A_log[(size_t)(d0 + 1) * 16 + n]) * 1.44269504f;
  }
  const float2 dtwv = *(const float2*)(dtw_ + d0);
  const float2 dtbv = *(const float2*)(dtb_ + d0);
  f32x2 dtw2; dtw2.x = dtwv.x; dtw2.y = dtwv.y;
  f32x2 dtb2; dtb2.x = dtbv.x; dtb2.y = dtbv.y;
  f32x2 s[16];
#pragma unroll
  for (int n = 0; n < 16; ++n) s[n] = sp2(0.f);
  f32x2 Tsum = sp2(0.f);
  const u16* xp = xs + mrow * DINNER + d0;
  u32 xw = *(const u32*)xp;
#pragma unroll 2
  for (int t = 0; t < LC; ++t) {
    f32x2 xv; xv.x = lo_bf(xw); xv.y = hi_bf(xw);
    if (t + 1 < LC) xw = *(const u32*)(xp + (size_t)(t + 1) * DINNER);
    f32x2 dtv = pkfma(sp2(DTin[t]), dtw2, dtb2);
    f32x2 sp; sp.x = softplus(dtv.x); sp.y = softplus(dtv.y);
    Tsum += sp;
    const float4* Br = (const float4*)&Bsh[t][0];
#pragma unroll
    for (int q = 0; q < 4; ++q) {
      const float4 Bq = Br[q];
      const float bqa[4] = {Bq.x, Bq.y, Bq.z, Bq.w};
#pragma unroll
      for (int j = 0; j < 4; ++j) {
        const int n = q * 4 + j;
        f32x2 e = An2[n] * sp;
        f32x2 dk; dk.x = fexp2(e.x); dk.y = fexp2(e.y);
        s[n] = pkfma(dk, s[n], sp2(bqa[j]) * xv);
      }
    }
  }
  const size_t so = ((size_t)(b * NC + c) * DINNER + d0) * 16;
  ushort8_t o0, o1, o2, o3;
#pragma unroll
  for (int j = 0; j < 8; ++j) {
    o0[j] = f2bf(s[j].x);     o1[j] = f2bf(s[8 + j].x);
    o2[j] = f2bf(s[j].y);     o3[j] = f2bf(s[8 + j].y);
  }
  *(ushort8_t*)(S + so) = o0;       *(ushort8_t*)(S + so + 8) = o1;
  *(ushort8_t*)(S + so + 16) = o2;  *(ushort8_t*)(S + so + 24) = o3;
  *(float2*)(Tdt + (size_t)(b * NC + c) * DINNER + d0) = make_float2(Tsum.x, Tsum.y);
}

// ---- phase 2: cross-chunk combine; S becomes per-chunk INIT state ----
__global__ __launch_bounds__(256) void scan_phase2(const float* __restrict__ A_log,
                                                   u16* __restrict__ S,
                                                   const float* __restrict__ Tdt,
                                                   float* __restrict__ out_state) {
  const int idx = blockIdx.x * 256 + threadIdx.x;  // B*DINNER*4
  const int nq = idx & 3;
  const int d = (idx >> 2) & (DINNER - 1);
  const int b = idx >> 13;
  float An2[4];
#pragma unroll
  for (int n = 0; n < 4; ++n) An2[n] = -__expf(A_log[d * 16 + nq * 4 + n]) * 1.44269504f;
  float prev[4] = {0.f, 0.f, 0.f, 0.f};
  for (int c = 0; c < NC; ++c) {
    const size_t base = (size_t)(b * NC + c) * DINNER + d;
    const float T = Tdt[base];
    const size_t so = base * 16 + nq * 4;
    ushort4 lv = *(const ushort4*)(S + so);
    const float loc[4] = {bf2f(lv.x), bf2f(lv.y), bf2f(lv.z), bf2f(lv.w)};
    ushort4 pv;
    pv.x = f2bf(prev[0]); pv.y = f2bf(prev[1]); pv.z = f2bf(prev[2]); pv.w = f2bf(prev[3]);
    *(ushort4*)(S + so) = pv;
    const float dk0 = fexp2(An2[0] * T), dk1 = fexp2(An2[1] * T);
    const float dk2 = fexp2(An2[2] * T), dk3 = fexp2(An2[3] * T);
    prev[0] = fmaf(dk0, prev[0], loc[0]);
    prev[1] = fmaf(dk1, prev[1], loc[1]);
    prev[2] = fmaf(dk2, prev[2], loc[2]);
    prev[3] = fmaf(dk3, prev[3], loc[3]);
  }
  *(float4*)(out_state + ((size_t)b * DINNER + d) * 16 + nq * 4) =
      make_float4(prev[0], prev[1], prev[2], prev[3]);
}

// ---- phase 3: re-scan chunk from init state, emit silu(y) ----
__global__ __launch_bounds__(128) void scan_phase3(const float* __restrict__ proj,
                                                   const u16* __restrict__ xs,
                                                   const float* __restrict__ dtw_,
                                                   const float* __restrict__ dtb_,
                                                   const float* __restrict__ A_log,
                                                   const float* __restrict__ Dp,
                                                   const u16* __restrict__ S,
                                                   u16* __restrict__ ysil) {
  __shared__ float Bsh[LC][16];
  __shared__ float Csh[LC][16];
  __shared__ float DTin[LC];
  const int tid = threadIdx.x;
  const int d0 = blockIdx.x * 256 + tid * 2;
  const int c = blockIdx.y;
  const int b = blockIdx.z;
  const size_t mrow = (size_t)b * SEQ + c * LC;
  for (int i = tid; i < LC * 16; i += 128) {
    int t = i >> 4, n = i & 15;
    Bsh[t][n] = proj[(mrow + t) * NPROJ_PAD + 1 + n];
    Csh[t][n] = proj[(mrow + t) * NPROJ_PAD + 17 + n];
  }
  if (tid < LC) DTin[tid] = proj[(mrow + tid) * NPROJ_PAD];
  __syncthreads();
  f32x2 An2[16];
#pragma unroll
  for (int n = 0; n < 16; ++n) {
    An2[n].x = -__expf(A_log[(size_t)d0 * 16 + n]) * 1.44269504f;
    An2[n].y = -__expf(A_log[(size_t)(d0 + 1) * 16 + n]) * 1.44269504f;
  }
  const float2 dtwv = *(const float2*)(dtw_ + d0);
  const float2 dtbv = *(const float2*)(dtb_ + d0);
  const float2 Ddv = *(const float2*)(Dp + d0);
  f32x2 dtw2; dtw2.x = dtwv.x; dtw2.y = dtwv.y;
  f32x2 dtb2; dtb2.x = dtbv.x; dtb2.y = dtbv.y;
  f32x2 Dd2; Dd2.x = Ddv.x; Dd2.y = Ddv.y;
  f32x2 s[16];
  const size_t so = ((size_t)(b * NC + c) * DINNER + d0) * 16;
  {
    ushort8_t v0 = *(const ushort8_t*)(S + so);
    ushort8_t v1 = *(const ushort8_t*)(S + so + 8);
    ushort8_t v2 = *(const ushort8_t*)(S + so + 16);
    ushort8_t v3 = *(const ushort8_t*)(S + so + 24);
#pragma unroll
    for (int j = 0; j < 8; ++j) {
      s[j].x = bf2f((u16)v0[j]);     s[8 + j].x = bf2f((u16)v1[j]);
      s[j].y = bf2f((u16)v2[j]);     s[8 + j].y = bf2f((u16)v3[j]);
    }
  }
  const u16* xp = xs + mrow * DINNER + d0;
  u16* yp = ysil + mrow * DINNER + d0;
  u32 xw = *(const u32*)xp;
#pragma unroll 2
  for (int t = 0; t < LC; ++t) {
    f32x2 xv; xv.x = lo_bf(xw); xv.y = hi_bf(xw);
    if (t + 1 < LC) xw = *(const u32*)(xp + (size_t)(t + 1) * DINNER);
    f32x2 dtv = pkfma(sp2(DTin[t]), dtw2, dtb2);
    f32x2 sp; sp.x = softplus(dtv.x); sp.y = softplus(dtv.y);
    f32x2 y = Dd2 * xv;
    const float4* Br = (const float4*)&Bsh[t][0];
    const float4* Cr = (const float4*)&Csh[t][0];
#pragma unroll
    for (int q = 0; q < 4; ++q) {
      const float4 Bq = Br[q];
      const float4 Cq = Cr[q];
      const float bqa[4] = {Bq.x, Bq.y, Bq.z, Bq.w};
      const float cqa[4] = {Cq.x, Cq.y, Cq.z, Cq.w};
#pragma unroll
      for (int j = 0; j < 4; ++j) {
        const int n = q * 4 + j;
        f32x2 e = An2[n] * sp;
        f32x2 dk; dk.x = fexp2(e.x); dk.y = fexp2(e.y);
        s[n] = pkfma(dk, s[n], sp2(bqa[j]) * xv);
        y = pkfma(sp2(cqa[j]), s[n], y);
      }
    }
    const float sy0 = y.x / (1.f + __expf(-y.x));
    const float sy1 = y.y / (1.f + __expf(-y.y));
    const u32 ow = (u32)f2bf(sy0) | ((u32)f2bf(sy1) << 16);
    *(u32*)(yp + (size_t)t * DINNER) = ow;
  }
}

// ---------------- launch ----------------
extern "C" void kernel_launch(void* const* d_in, const int* in_sizes, int n_in,
                              void* d_out, int out_size, void* d_ws, size_t ws_size,
                              hipStream_t stream) {
  const float* x = (const float*)d_in[0];
  const float* in_proj_w = (const float*)d_in[1];
  const float* conv_w = (const float*)d_in[2];
  const float* x_proj_w = (const float*)d_in[3];
  const float* dt_proj_w = (const float*)d_in[4];
  const float* dt_proj_b = (const float*)d_in[5];
  const float* A_log = (const float*)d_in[6];
  const float* Dvec = (const float*)d_in[7];
  const float* out_proj_w = (const float*)d_in[8];
  const float* norm_w = (const float*)d_in[9];
  const float* norm_b = (const float*)d_in[10];

  char* ws = (char*)d_ws;
  u16* h = (u16*)(ws + 0);                    // 8192x1024 bf16 (16 MB)
  u16* w1b = (u16*)(ws + 16777216);           // 2048x1024 bf16 (4 MB)
  u16* w3b = (u16*)(ws + 20971520);           // 1024x2048 bf16 (4 MB)
  u16* w2b = (u16*)(ws + 25165824);           // 48x2048 bf16 (0.19 MB)
  u16* c1 = (u16*)(ws + 25362432);            // 8192x2048 bf16 (32 MB)
  u16* ysil = c1;                             // aliased: c1 dead after conv
  u16* cs = (u16*)(ws + 58916864);            // 8192x2048 bf16 (32 MB)
  float* proj = (float*)(ws + 92471296);      // 8192x48 fp32 (1.5 MB)
  u16* Sbuf = (u16*)(ws + 94044160);          // [b][c][d][16] bf16 (16 MB)
  float* Tdt = (float*)(ws + 110821376);      // [b][c][d] fp32 (2 MB)

  float* out = (float*)d_out;
  float* out_state = out + (size_t)4 * SEQ * DIM;

  cast_w_kernel<<<2048, 256, 0, stream>>>(in_proj_w, out_proj_w, w1b, w3b);
  cast_w2pad_kernel<<<384, 256, 0, stream>>>(x_proj_w, w2b);
  ln_kernel<<<8192, 256, 0, stream>>>(x, norm_w, norm_b, h);
  gemm_bf16_kernel<<<dim3(DINNER / 128, 64), 512, 0, stream>>>(h, w1b, c1, DIM, DINNER);
  conv_silu_kernel<<<1024, 256, 0, stream>>>(c1, conv_w, cs);
  gemm_w2_kernel<<<128, 256, 0, stream>>>(cs, w2b, proj);
  scan_phase1<<<dim3(DINNER / 256, NC, 4), 128, 0, stream>>>(proj, cs, dt_proj_w, dt_proj_b,
                                                             A_log, Sbuf, Tdt);
  scan_phase2<<<128, 256, 0, stream>>>(A_log, Sbuf, Tdt, out_state);
  scan_phase3<<<dim3(DINNER / 256, NC, 4), 128, 0, stream>>>(proj, cs, dt_proj_w, dt_proj_b,
                                                             A_log, Dvec, Sbuf, ysil);
  gemm_out_kernel<<<dim3(DIM / 128, 64), 512, 0, stream>>>(ysil, w3b, x, out, DINNER, DIM);
}